// Round 1
// baseline (39425.793 us; speedup 1.0000x reference)
//
#include <hip/hip_runtime.h>
#include <math.h>

#define NN 100000
#define NE 1600000
#define HID 64

// ---- monotonic float<->uint encoding for atomicMax on floats ----
__device__ __forceinline__ unsigned fenc(float f) {
    unsigned b = __float_as_uint(f);
    return (b & 0x80000000u) ? ~b : (b | 0x80000000u);
}
__device__ __forceinline__ float fdec(unsigned u) {
    unsigned b = (u & 0x80000000u) ? (u & 0x7FFFFFFFu) : ~u;
    return __uint_as_float(b);
}

// ---- per-layer prep: sum(a) scalar, init max/Z ----
__global__ void prep_kernel(const float* __restrict__ a, float* sum_a,
                            unsigned* m_enc, double* Z) {
    int t = threadIdx.x; // 128 threads
    float v = a[t];
    #pragma unroll
    for (int o = 32; o >= 1; o >>= 1) v += __shfl_xor(v, o);
    __shared__ float sh[2];
    if ((t & 63) == 0) sh[t >> 6] = v;
    __syncthreads();
    if (t == 0) {
        *sum_a = sh[0] + sh[1];
        *m_enc = fenc(-INFINITY);
        *Z = 0.0;
    }
}

// ---- GEMM: Wh[n][64] = h[n][K] @ W[K][64] ----
template <int K>
__global__ void gemm_k(const float* __restrict__ h, const float* __restrict__ W,
                       float* __restrict__ Wh, int n) {
    __shared__ float Wl[K][HID];
    int t = threadIdx.x;
    for (int i = t; i < K * HID; i += 256) Wl[i / HID][i % HID] = W[i];
    __syncthreads();
    int node = blockIdx.x * 64 + (t >> 2);
    int c0 = (t & 3) * 16;
    if (node >= n) return;
    float acc[16];
    #pragma unroll
    for (int j = 0; j < 16; j++) acc[j] = 0.f;
    const float* hr = h + (size_t)node * K;
    #pragma unroll
    for (int k = 0; k < K; k++) {
        float v = hr[k];
        #pragma unroll
        for (int j = 0; j < 16; j++) acc[j] += v * Wl[k][c0 + j];
    }
    float* o = Wh + (size_t)node * HID + c0;
    #pragma unroll
    for (int j = 0; j < 16; j += 4)
        *(float4*)(o + j) = make_float4(acc[j], acc[j+1], acc[j+2], acc[j+3]);
}

// ---- edge pass 1: e = lrelu(dot(Wh[src],Wh[dst]) * sum_a); global max ----
__global__ void edge_pass1(const float* __restrict__ Wh, const int* __restrict__ src,
                           const int* __restrict__ dst, const float* __restrict__ sum_a,
                           float* __restrict__ ebuf, unsigned* m_enc, int nE) {
    int t = threadIdx.x;
    int lane16 = t & 15;
    int eidx = blockIdx.x * 16 + (t >> 4);
    float s = 0.f;
    bool valid = eidx < nE;
    if (valid) {
        int si = src[eidx], di = dst[eidx];
        float4 a4 = *(const float4*)(Wh + (size_t)si * HID + lane16 * 4);
        float4 b4 = *(const float4*)(Wh + (size_t)di * HID + lane16 * 4);
        s = a4.x * b4.x + a4.y * b4.y + a4.z * b4.z + a4.w * b4.w;
    }
    #pragma unroll
    for (int o = 8; o >= 1; o >>= 1) s += __shfl_xor(s, o, 16);
    float sa = *sum_a;
    float e = s * sa;
    e = e > 0.f ? e : 0.2f * e;          // leaky_relu slope 0.2
    if (valid && lane16 == 0) ebuf[eidx] = e;
    float mv = valid ? e : -INFINITY;
    #pragma unroll
    for (int o = 16; o <= 32; o <<= 1) mv = fmaxf(mv, __shfl_xor(mv, o));
    if ((t & 63) == 0) atomicMax(m_enc, fenc(mv));
}

// ---- edge pass 2: w = exp(e - m); Z += w; acc[dst] += w * Wh[src] ----
__global__ void edge_pass2(const float* __restrict__ Wh, const int* __restrict__ src,
                           const int* __restrict__ dst, const float* __restrict__ ebuf,
                           const unsigned* __restrict__ m_enc, double* Z,
                           float* __restrict__ acc, int nE) {
    float m = fdec(*m_enc);
    int t = threadIdx.x;
    int lane16 = t & 15;
    int eidx = blockIdx.x * 16 + (t >> 4);
    bool valid = eidx < nE;
    float w = 0.f;
    if (valid) {
        w = expf(ebuf[eidx] - m);
        int si = src[eidx], di = dst[eidx];
        float4 a4 = *(const float4*)(Wh + (size_t)si * HID + lane16 * 4);
        float* ap = acc + (size_t)di * HID + lane16 * 4;
        atomicAdd(ap + 0, w * a4.x);
        atomicAdd(ap + 1, w * a4.y);
        atomicAdd(ap + 2, w * a4.z);
        atomicAdd(ap + 3, w * a4.w);
    }
    // per-wave Z partial: only one lane per edge contributes
    float zv = (valid && lane16 == 0) ? w : 0.f;
    zv += __shfl_xor(zv, 16);
    zv += __shfl_xor(zv, 32);
    if ((t & 63) == 0) atomicAdd(Z, (double)zv);
}

// ---- node pass: h' = elu(acc / Z); out = LN(h') ----
__global__ void node_pass(const float* __restrict__ acc, const double* __restrict__ Z,
                          const float* __restrict__ g, const float* __restrict__ b,
                          float* __restrict__ out, int n) {
    float invZ = (float)(1.0 / Z[0]);
    int node = blockIdx.x * 4 + (threadIdx.x >> 6);
    int d = threadIdx.x & 63;
    if (node >= n) return;
    float v = acc[(size_t)node * HID + d] * invZ;
    v = v > 0.f ? v : expm1f(v);         // elu
    float s = v, s2 = v * v;
    #pragma unroll
    for (int o = 32; o >= 1; o >>= 1) {
        s += __shfl_xor(s, o);
        s2 += __shfl_xor(s2, o);
    }
    float mean = s * (1.f / 64.f);
    float var = s2 * (1.f / 64.f) - mean * mean;
    float o = g[d] * (v - mean) * rsqrtf(var + 1e-5f) + b[d];
    out[(size_t)node * HID + d] = o;
}

// ---- final: out = sigmoid(relu((sp+tp)@cW1+cb1)@cW2+cb2) ----
__global__ void final_kernel(const float* __restrict__ sp, const float* __restrict__ tp,
                             const float* __restrict__ cW1, const float* __restrict__ cb1,
                             const float* __restrict__ cW2, const float* __restrict__ cb2,
                             float* __restrict__ out, int n) {
    __shared__ float W1[64 * 32];
    __shared__ float W2[32];
    __shared__ float B1[32];
    __shared__ float hsh[8][64];
    int t = threadIdx.x;
    for (int i = t; i < 2048; i += 256) W1[i] = cW1[i];
    if (t < 32) { W2[t] = cW2[t]; B1[t] = cb1[t]; }
    __syncthreads();
    int ln = t >> 5;
    int j = t & 31;
    int node = blockIdx.x * 8 + ln;
    if (node < n) {
        hsh[ln][j]      = sp[(size_t)node * 64 + j]      + tp[(size_t)node * 64 + j];
        hsh[ln][j + 32] = sp[(size_t)node * 64 + j + 32] + tp[(size_t)node * 64 + j + 32];
    }
    __syncthreads();
    if (node >= n) return;
    float a = B1[j];
    #pragma unroll
    for (int k = 0; k < 64; k++) a += hsh[ln][k] * W1[k * 32 + j];
    a = fmaxf(a, 0.f);
    float p = a * W2[j];
    #pragma unroll
    for (int o = 16; o >= 1; o >>= 1) p += __shfl_xor(p, o, 32);
    if (j == 0) out[node] = 1.f / (1.f + expf(-(p + cb2[0])));
}

extern "C" void kernel_launch(void* const* d_in, const int* in_sizes, int n_in,
                              void* d_out, int out_size, void* d_ws, size_t ws_size,
                              hipStream_t stream) {
    const float* x   = (const float*)d_in[0];
    const int*   ei  = (const int*)d_in[1];
    const int*   tei = (const int*)d_in[3];
    const float* sW0 = (const float*)d_in[4],  *sa0 = (const float*)d_in[5];
    const float* sg0 = (const float*)d_in[6],  *sb0 = (const float*)d_in[7];
    const float* sW1 = (const float*)d_in[8],  *sa1 = (const float*)d_in[9];
    const float* sg1 = (const float*)d_in[10], *sb1 = (const float*)d_in[11];
    const float* tW0 = (const float*)d_in[12], *ta0 = (const float*)d_in[13];
    const float* tg0 = (const float*)d_in[14], *tb0 = (const float*)d_in[15];
    const float* tW1 = (const float*)d_in[16], *ta1 = (const float*)d_in[17];
    const float* tg1 = (const float*)d_in[18], *tb1 = (const float*)d_in[19];
    const float* cW1 = (const float*)d_in[20], *cb1 = (const float*)d_in[21];
    const float* cW2 = (const float*)d_in[22], *cb2 = (const float*)d_in[23];
    float* out = (float*)d_out;

    float* ws = (float*)d_ws;
    float* buf_h   = ws;
    float* buf_Wh  = ws + (size_t)NN * HID;
    float* buf_acc = ws + 2 * (size_t)NN * HID;
    float* buf_sp  = ws + 3 * (size_t)NN * HID;
    float* ebuf    = ws + 4 * (size_t)NN * HID;
    size_t sc = 4 * (size_t)NN * HID + NE;      // even -> 8B aligned
    double*   Zp    = (double*)(ws + sc);
    float*    sum_a = ws + sc + 2;
    unsigned* m_enc = (unsigned*)(ws + sc + 3);

    auto run_layer = [&](const float* hin, int K, const float* W, const float* a,
                         const float* g, const float* b, const int* src, const int* dst) {
        hipMemsetAsync(buf_acc, 0, (size_t)NN * HID * sizeof(float), stream);
        prep_kernel<<<1, 128, 0, stream>>>(a, sum_a, m_enc, Zp);
        if (K == 8)
            gemm_k<8><<<(NN + 63) / 64, 256, 0, stream>>>(hin, W, buf_Wh, NN);
        else
            gemm_k<64><<<(NN + 63) / 64, 256, 0, stream>>>(hin, W, buf_Wh, NN);
        edge_pass1<<<(NE + 15) / 16, 256, 0, stream>>>(buf_Wh, src, dst, sum_a, ebuf, m_enc, NE);
        edge_pass2<<<(NE + 15) / 16, 256, 0, stream>>>(buf_Wh, src, dst, ebuf, m_enc, Zp, buf_acc, NE);
        node_pass<<<(NN + 3) / 4, 256, 0, stream>>>(buf_acc, Zp, g, b, buf_h, NN);
    };

    // spatial stack
    run_layer(x,     8,  sW0, sa0, sg0, sb0, ei, ei + NE);
    run_layer(buf_h, 64, sW1, sa1, sg1, sb1, ei, ei + NE);
    hipMemcpyAsync(buf_sp, buf_h, (size_t)NN * HID * sizeof(float),
                   hipMemcpyDeviceToDevice, stream);
    // temporal stack
    run_layer(x,     8,  tW0, ta0, tg0, tb0, tei, tei + NE);
    run_layer(buf_h, 64, tW1, ta1, tg1, tb1, tei, tei + NE);

    final_kernel<<<(NN + 7) / 8, 256, 0, stream>>>(buf_sp, buf_h, cW1, cb1, cW2, cb2, out, NN);
}

// Round 2
// 19626.154 us; speedup vs baseline: 2.0088x; 2.0088x over previous
//
#include <hip/hip_runtime.h>
#include <math.h>

#define NN 100000
#define NE 1600000
#define HID 64

// ---- monotonic float<->uint encoding for atomicMax on floats ----
__device__ __forceinline__ unsigned fenc(float f) {
    unsigned b = __float_as_uint(f);
    return (b & 0x80000000u) ? ~b : (b | 0x80000000u);
}
__device__ __forceinline__ float fdec(unsigned u) {
    unsigned b = (u & 0x80000000u) ? (u & 0x7FFFFFFFu) : ~u;
    return __uint_as_float(b);
}

// ---- per-layer prep: sum(a) scalar, init max/Z ----
__global__ void prep_kernel(const float* __restrict__ a, float* sum_a,
                            unsigned* m_enc, double* Z) {
    int t = threadIdx.x; // 128 threads
    float v = a[t];
    #pragma unroll
    for (int o = 32; o >= 1; o >>= 1) v += __shfl_xor(v, o);
    __shared__ float sh[2];
    if ((t & 63) == 0) sh[t >> 6] = v;
    __syncthreads();
    if (t == 0) {
        *sum_a = sh[0] + sh[1];
        *m_enc = fenc(-INFINITY);
        *Z = 0.0;
    }
}

// ================= CSR build =================
__global__ void hist_k(const int* __restrict__ dst, int* __restrict__ deg, int nE) {
    int e = blockIdx.x * 256 + threadIdx.x;
    if (e < nE) atomicAdd(&deg[dst[e]], 1);
}

// block-level exclusive scan, 1024 elems/block (256 thr x 4)
__global__ void scanA(const int* __restrict__ deg, int* __restrict__ rowtmp,
                      int* __restrict__ bsum, int n) {
    __shared__ int sh[256];
    int t = threadIdx.x;
    int base = blockIdx.x * 1024 + t * 4;
    int a0 = (base + 0 < n) ? deg[base + 0] : 0;
    int a1 = (base + 1 < n) ? deg[base + 1] : 0;
    int a2 = (base + 2 < n) ? deg[base + 2] : 0;
    int a3 = (base + 3 < n) ? deg[base + 3] : 0;
    int s = a0 + a1 + a2 + a3;
    sh[t] = s;
    __syncthreads();
    for (int off = 1; off < 256; off <<= 1) {
        int x = (t >= off) ? sh[t - off] : 0;
        __syncthreads();
        sh[t] += x;
        __syncthreads();
    }
    int excl = sh[t] - s;
    if (t == 255) bsum[blockIdx.x] = sh[255];
    if (base + 0 < n) rowtmp[base + 0] = excl;
    if (base + 1 < n) rowtmp[base + 1] = excl + a0;
    if (base + 2 < n) rowtmp[base + 2] = excl + a0 + a1;
    if (base + 3 < n) rowtmp[base + 3] = excl + a0 + a1 + a2;
}

__global__ void scanB(int* __restrict__ bsum, int nb) {
    __shared__ int sh[256];
    int t = threadIdx.x;
    int v = (t < nb) ? bsum[t] : 0;
    sh[t] = v;
    __syncthreads();
    for (int off = 1; off < 256; off <<= 1) {
        int x = (t >= off) ? sh[t - off] : 0;
        __syncthreads();
        sh[t] += x;
        __syncthreads();
    }
    if (t < nb) bsum[t] = sh[t] - v; // exclusive
}

__global__ void scanC(const int* __restrict__ rowtmp, const int* __restrict__ bsum,
                      int* __restrict__ rowptr, int n, int total) {
    int i = blockIdx.x * 256 + threadIdx.x;
    if (i < n) rowptr[i] = rowtmp[i] + bsum[i >> 10];
    if (i == n) rowptr[n] = total;
}

__global__ void csr_fill(const int* __restrict__ src, const int* __restrict__ dst,
                         int* __restrict__ cursor, int* __restrict__ csrs,
                         int* __restrict__ cpos, int nE) {
    int e = blockIdx.x * 256 + threadIdx.x;
    if (e >= nE) return;
    int d = dst[e];
    int p = atomicAdd(&cursor[d], 1);
    csrs[p] = src[e];
    cpos[e] = p;
}

// ---- GEMM: Wh[n][64] = h[n][K] @ W[K][64] ----
template <int K>
__global__ void gemm_k(const float* __restrict__ h, const float* __restrict__ W,
                       float* __restrict__ Wh, int n) {
    __shared__ float Wl[K][HID];
    int t = threadIdx.x;
    for (int i = t; i < K * HID; i += 256) Wl[i / HID][i % HID] = W[i];
    __syncthreads();
    int node = blockIdx.x * 64 + (t >> 2);
    int c0 = (t & 3) * 16;
    if (node >= n) return;
    float acc[16];
    #pragma unroll
    for (int j = 0; j < 16; j++) acc[j] = 0.f;
    const float* hr = h + (size_t)node * K;
    #pragma unroll
    for (int k = 0; k < K; k++) {
        float v = hr[k];
        #pragma unroll
        for (int j = 0; j < 16; j++) acc[j] += v * Wl[k][c0 + j];
    }
    float* o = Wh + (size_t)node * HID + c0;
    #pragma unroll
    for (int j = 0; j < 16; j += 4)
        *(float4*)(o + j) = make_float4(acc[j], acc[j+1], acc[j+2], acc[j+3]);
}

// ---- edge pass 1: e = lrelu(dot(Wh[src],Wh[dst]) * sum_a) -> ebuf[csr order]; global max ----
__global__ void edge_pass1(const float* __restrict__ Wh, const int* __restrict__ src,
                           const int* __restrict__ dst, const float* __restrict__ sum_a,
                           const int* __restrict__ cpos, float* __restrict__ ebuf,
                           unsigned* m_enc, int nE) {
    int t = threadIdx.x;
    int lane16 = t & 15;
    int eidx = blockIdx.x * 16 + (t >> 4);
    float s = 0.f;
    bool valid = eidx < nE;
    if (valid) {
        int si = src[eidx], di = dst[eidx];
        float4 a4 = *(const float4*)(Wh + (size_t)si * HID + lane16 * 4);
        float4 b4 = *(const float4*)(Wh + (size_t)di * HID + lane16 * 4);
        s = a4.x * b4.x + a4.y * b4.y + a4.z * b4.z + a4.w * b4.w;
    }
    #pragma unroll
    for (int o = 8; o >= 1; o >>= 1) s += __shfl_xor(s, o, 16);
    float e = s * (*sum_a);
    e = e > 0.f ? e : 0.2f * e;          // leaky_relu slope 0.2
    if (valid && lane16 == 0) ebuf[cpos[eidx]] = e;
    float mv = valid ? e : -INFINITY;
    mv = fmaxf(mv, __shfl_xor(mv, 16));
    mv = fmaxf(mv, __shfl_xor(mv, 32));
    if ((t & 63) == 0) atomicMax(m_enc, fenc(mv));
}

// ---- Z reduce: w = exp(e - m) in place; Z += sum(w) ----
__global__ void zred(float* __restrict__ ebuf, const unsigned* __restrict__ m_enc,
                     double* __restrict__ Z, int nE) {
    int i = blockIdx.x * 256 + threadIdx.x;
    float m = fdec(*m_enc);
    float w = 0.f;
    if (i < nE) { w = expf(ebuf[i] - m); ebuf[i] = w; }
    float sw = w;
    #pragma unroll
    for (int o = 32; o >= 1; o >>= 1) sw += __shfl_xor(sw, o);
    __shared__ float sh[4];
    if ((threadIdx.x & 63) == 0) sh[threadIdx.x >> 6] = sw;
    __syncthreads();
    if (threadIdx.x == 0) atomicAdd(Z, (double)(sh[0] + sh[1] + sh[2] + sh[3]));
}

// ---- gather-aggregate + elu + LayerNorm, one wave per node ----
__global__ void agg_ln(const float* __restrict__ Wh, const int* __restrict__ rowptr,
                       const int* __restrict__ csrs, const float* __restrict__ wbuf,
                       const double* __restrict__ Z, const float* __restrict__ g,
                       const float* __restrict__ b, float* __restrict__ out, int n) {
    int node = blockIdx.x * 4 + (threadIdx.x >> 6);
    int lane = threadIdx.x & 63;
    if (node >= n) return;
    float invZ = (float)(1.0 / Z[0]);
    int beg = rowptr[node], end = rowptr[node + 1];
    float acc = 0.f;
    for (int i = beg; i < end; i++) {
        int si = csrs[i];        // wave-uniform broadcast load
        float w = wbuf[i];       // wave-uniform broadcast load
        acc += w * Wh[(size_t)si * HID + lane];   // coalesced 256B row
    }
    float v = acc * invZ;
    v = v > 0.f ? v : expm1f(v);         // elu
    float s = v, s2 = v * v;
    #pragma unroll
    for (int o = 32; o >= 1; o >>= 1) {
        s += __shfl_xor(s, o);
        s2 += __shfl_xor(s2, o);
    }
    float mean = s * (1.f / 64.f);
    float var = s2 * (1.f / 64.f) - mean * mean;
    out[(size_t)node * HID + lane] = g[lane] * (v - mean) * rsqrtf(var + 1e-5f) + b[lane];
}

// ---- final: out = sigmoid(relu((sp+tp)@cW1+cb1)@cW2+cb2) ----
__global__ void final_kernel(const float* __restrict__ sp, const float* __restrict__ tp,
                             const float* __restrict__ cW1, const float* __restrict__ cb1,
                             const float* __restrict__ cW2, const float* __restrict__ cb2,
                             float* __restrict__ out, int n) {
    __shared__ float W1[64 * 32];
    __shared__ float W2[32];
    __shared__ float B1[32];
    __shared__ float hsh[8][64];
    int t = threadIdx.x;
    for (int i = t; i < 2048; i += 256) W1[i] = cW1[i];
    if (t < 32) { W2[t] = cW2[t]; B1[t] = cb1[t]; }
    __syncthreads();
    int ln = t >> 5;
    int j = t & 31;
    int node = blockIdx.x * 8 + ln;
    if (node < n) {
        hsh[ln][j]      = sp[(size_t)node * 64 + j]      + tp[(size_t)node * 64 + j];
        hsh[ln][j + 32] = sp[(size_t)node * 64 + j + 32] + tp[(size_t)node * 64 + j + 32];
    }
    __syncthreads();
    if (node >= n) return;
    float a = B1[j];
    #pragma unroll
    for (int k = 0; k < 64; k++) a += hsh[ln][k] * W1[k * 32 + j];
    a = fmaxf(a, 0.f);
    float p = a * W2[j];
    #pragma unroll
    for (int o = 16; o >= 1; o >>= 1) p += __shfl_xor(p, o, 32);
    if (j == 0) out[node] = 1.f / (1.f + expf(-(p + cb2[0])));
}

extern "C" void kernel_launch(void* const* d_in, const int* in_sizes, int n_in,
                              void* d_out, int out_size, void* d_ws, size_t ws_size,
                              hipStream_t stream) {
    const float* x   = (const float*)d_in[0];
    const int*   ei  = (const int*)d_in[1];
    const int*   tei = (const int*)d_in[3];
    const float* sW0 = (const float*)d_in[4],  *sa0 = (const float*)d_in[5];
    const float* sg0 = (const float*)d_in[6],  *sb0 = (const float*)d_in[7];
    const float* sW1 = (const float*)d_in[8],  *sa1 = (const float*)d_in[9];
    const float* sg1 = (const float*)d_in[10], *sb1 = (const float*)d_in[11];
    const float* tW0 = (const float*)d_in[12], *ta0 = (const float*)d_in[13];
    const float* tg0 = (const float*)d_in[14], *tb0 = (const float*)d_in[15];
    const float* tW1 = (const float*)d_in[16], *ta1 = (const float*)d_in[17];
    const float* tg1 = (const float*)d_in[18], *tb1 = (const float*)d_in[19];
    const float* cW1 = (const float*)d_in[20], *cb1 = (const float*)d_in[21];
    const float* cW2 = (const float*)d_in[22], *cb2 = (const float*)d_in[23];
    float* out = (float*)d_out;

    float* ws = (float*)d_ws;
    size_t o = 0;
    float* buf_h  = ws + o; o += (size_t)NN * HID;
    float* buf_Wh = ws + o; o += (size_t)NN * HID;
    float* buf_sp = ws + o; o += (size_t)NN * HID;
    float* ebuf   = ws + o; o += NE;
    double*   Zp    = (double*)(ws + o); o += 2;   // offset even -> 8B aligned
    float*    sum_a = ws + o; o += 1;
    unsigned* m_enc = (unsigned*)(ws + o); o += 1;
    int* ip = (int*)(ws + o);
    int* rowptrS = ip; ip += NN + 1;
    int* csrsS   = ip; ip += NE;
    int* cposS   = ip; ip += NE;
    int* rowptrT = ip; ip += NN + 1;
    int* csrsT   = ip; ip += NE;
    int* cposT   = ip; ip += NE;
    int* deg     = ip; ip += NN;    // reused as cursor
    int* rowtmp  = ip; ip += NN;
    int* bsum    = ip; ip += 256;

    const int NB_SCAN = (NN + 1023) / 1024;  // 98

    auto build_csr = [&](const int* src, const int* dst, int* rowptr, int* csrs, int* cpos) {
        hipMemsetAsync(deg, 0, NN * sizeof(int), stream);
        hist_k<<<(NE + 255) / 256, 256, 0, stream>>>(dst, deg, NE);
        scanA<<<NB_SCAN, 256, 0, stream>>>(deg, rowtmp, bsum, NN);
        scanB<<<1, 256, 0, stream>>>(bsum, NB_SCAN);
        scanC<<<(NN + 1 + 255) / 256, 256, 0, stream>>>(rowtmp, bsum, rowptr, NN, NE);
        hipMemcpyAsync(deg, rowptr, NN * sizeof(int), hipMemcpyDeviceToDevice, stream);
        csr_fill<<<(NE + 255) / 256, 256, 0, stream>>>(src, dst, deg, csrs, cpos, NE);
    };

    build_csr(ei,  ei  + NE, rowptrS, csrsS, cposS);
    build_csr(tei, tei + NE, rowptrT, csrsT, cposT);

    auto run_layer = [&](const float* hin, int K, const float* W, const float* a,
                         const float* g, const float* b, const int* src, const int* dst,
                         const int* rowptr, const int* csrs, const int* cpos, float* hout) {
        prep_kernel<<<1, 128, 0, stream>>>(a, sum_a, m_enc, Zp);
        if (K == 8)
            gemm_k<8><<<(NN + 63) / 64, 256, 0, stream>>>(hin, W, buf_Wh, NN);
        else
            gemm_k<64><<<(NN + 63) / 64, 256, 0, stream>>>(hin, W, buf_Wh, NN);
        edge_pass1<<<(NE + 15) / 16, 256, 0, stream>>>(buf_Wh, src, dst, sum_a, cpos, ebuf, m_enc, NE);
        zred<<<(NE + 255) / 256, 256, 0, stream>>>(ebuf, m_enc, Zp, NE);
        agg_ln<<<(NN + 3) / 4, 256, 0, stream>>>(buf_Wh, rowptr, csrs, ebuf, Zp, g, b, hout, NN);
    };

    // spatial stack
    run_layer(x,     8,  sW0, sa0, sg0, sb0, ei, ei + NE, rowptrS, csrsS, cposS, buf_h);
    run_layer(buf_h, 64, sW1, sa1, sg1, sb1, ei, ei + NE, rowptrS, csrsS, cposS, buf_sp);
    // temporal stack
    run_layer(x,     8,  tW0, ta0, tg0, tb0, tei, tei + NE, rowptrT, csrsT, cposT, buf_h);
    run_layer(buf_h, 64, tW1, ta1, tg1, tb1, tei, tei + NE, rowptrT, csrsT, cposT, buf_h);

    final_kernel<<<(NN + 7) / 8, 256, 0, stream>>>(buf_sp, buf_h, cW1, cb1, cW2, cb2, out, NN);
}

// Round 3
// 1785.291 us; speedup vs baseline: 22.0837x; 10.9932x over previous
//
#include <hip/hip_runtime.h>
#include <math.h>

#define NN 100000
#define NE 1600000
#define HID 64

// ---- monotonic float<->uint encoding for atomicMax on floats ----
__device__ __forceinline__ unsigned fenc(float f) {
    unsigned b = __float_as_uint(f);
    return (b & 0x80000000u) ? ~b : (b | 0x80000000u);
}
__device__ __forceinline__ float fdec(unsigned u) {
    unsigned b = (u & 0x80000000u) ? (u & 0x7FFFFFFFu) : ~u;
    return __uint_as_float(b);
}

// ---- per-layer prep: sum(a) scalar, init max/Z ----
__global__ void prep_kernel(const float* __restrict__ a, float* sum_a,
                            unsigned* m_enc, double* Z) {
    int t = threadIdx.x; // 128 threads
    float v = a[t];
    #pragma unroll
    for (int o = 32; o >= 1; o >>= 1) v += __shfl_xor(v, o);
    __shared__ float sh[2];
    if ((t & 63) == 0) sh[t >> 6] = v;
    __syncthreads();
    if (t == 0) {
        *sum_a = sh[0] + sh[1];
        *m_enc = fenc(-INFINITY);
        *Z = 0.0;
    }
}

// ================= CSR build =================
__global__ void hist_k(const int* __restrict__ dst, int* __restrict__ deg, int nE) {
    int e = blockIdx.x * 256 + threadIdx.x;
    if (e < nE) atomicAdd(&deg[dst[e]], 1);
}

// block-level exclusive scan, 1024 elems/block (256 thr x 4)
__global__ void scanA(const int* __restrict__ deg, int* __restrict__ rowtmp,
                      int* __restrict__ bsum, int n) {
    __shared__ int sh[256];
    int t = threadIdx.x;
    int base = blockIdx.x * 1024 + t * 4;
    int a0 = (base + 0 < n) ? deg[base + 0] : 0;
    int a1 = (base + 1 < n) ? deg[base + 1] : 0;
    int a2 = (base + 2 < n) ? deg[base + 2] : 0;
    int a3 = (base + 3 < n) ? deg[base + 3] : 0;
    int s = a0 + a1 + a2 + a3;
    sh[t] = s;
    __syncthreads();
    for (int off = 1; off < 256; off <<= 1) {
        int x = (t >= off) ? sh[t - off] : 0;
        __syncthreads();
        sh[t] += x;
        __syncthreads();
    }
    int excl = sh[t] - s;
    if (t == 255) bsum[blockIdx.x] = sh[255];
    if (base + 0 < n) rowtmp[base + 0] = excl;
    if (base + 1 < n) rowtmp[base + 1] = excl + a0;
    if (base + 2 < n) rowtmp[base + 2] = excl + a0 + a1;
    if (base + 3 < n) rowtmp[base + 3] = excl + a0 + a1 + a2;
}

__global__ void scanB(int* __restrict__ bsum, int nb) {
    __shared__ int sh[256];
    int t = threadIdx.x;
    int v = (t < nb) ? bsum[t] : 0;
    sh[t] = v;
    __syncthreads();
    for (int off = 1; off < 256; off <<= 1) {
        int x = (t >= off) ? sh[t - off] : 0;
        __syncthreads();
        sh[t] += x;
        __syncthreads();
    }
    if (t < nb) bsum[t] = sh[t] - v; // exclusive
}

__global__ void scanC(const int* __restrict__ rowtmp, const int* __restrict__ bsum,
                      int* __restrict__ rowptr, int n, int total) {
    int i = blockIdx.x * 256 + threadIdx.x;
    if (i < n) rowptr[i] = rowtmp[i] + bsum[i >> 10];
    if (i == n) rowptr[n] = total;
}

__global__ void csr_fill(const int* __restrict__ src, const int* __restrict__ dst,
                         int* __restrict__ cursor, int* __restrict__ csrs,
                         int* __restrict__ cpos, int nE) {
    int e = blockIdx.x * 256 + threadIdx.x;
    if (e >= nE) return;
    int d = dst[e];
    int p = atomicAdd(&cursor[d], 1);
    csrs[p] = src[e];
    cpos[e] = p;
}

// ---- GEMM: Wh[n][64] = h[n][K] @ W[K][64] ----
template <int K>
__global__ void gemm_k(const float* __restrict__ h, const float* __restrict__ W,
                       float* __restrict__ Wh, int n) {
    __shared__ float Wl[K][HID];
    int t = threadIdx.x;
    for (int i = t; i < K * HID; i += 256) Wl[i / HID][i % HID] = W[i];
    __syncthreads();
    int node = blockIdx.x * 64 + (t >> 2);
    int c0 = (t & 3) * 16;
    if (node >= n) return;
    float acc[16];
    #pragma unroll
    for (int j = 0; j < 16; j++) acc[j] = 0.f;
    const float* hr = h + (size_t)node * K;
    #pragma unroll
    for (int k = 0; k < K; k++) {
        float v = hr[k];
        #pragma unroll
        for (int j = 0; j < 16; j++) acc[j] += v * Wl[k][c0 + j];
    }
    float* o = Wh + (size_t)node * HID + c0;
    #pragma unroll
    for (int j = 0; j < 16; j += 4)
        *(float4*)(o + j) = make_float4(acc[j], acc[j+1], acc[j+2], acc[j+3]);
}

// ---- edge pass 1 (grid-stride): e -> ebuf[csr order]; block-local max, 1 atomic/block ----
__global__ void edge_pass1(const float* __restrict__ Wh, const int* __restrict__ src,
                           const int* __restrict__ dst, const float* __restrict__ sum_a,
                           const int* __restrict__ cpos, float* __restrict__ ebuf,
                           unsigned* m_enc, int nE) {
    int t = threadIdx.x;
    int lane16 = t & 15;
    int gid = (blockIdx.x * 256 + t) >> 4;          // global 16-lane-group id
    int stride = (gridDim.x * 256) >> 4;
    float sa = *sum_a;
    float mloc = -INFINITY;
    for (int eidx = gid; eidx < nE; eidx += stride) {
        int si = src[eidx], di = dst[eidx];
        float4 a4 = *(const float4*)(Wh + (size_t)si * HID + lane16 * 4);
        float4 b4 = *(const float4*)(Wh + (size_t)di * HID + lane16 * 4);
        float s = a4.x * b4.x + a4.y * b4.y + a4.z * b4.z + a4.w * b4.w;
        #pragma unroll
        for (int o = 8; o >= 1; o >>= 1) s += __shfl_xor(s, o, 16);
        float e = s * sa;
        e = e > 0.f ? e : 0.2f * e;          // leaky_relu slope 0.2
        if (lane16 == 0) ebuf[cpos[eidx]] = e;
        mloc = fmaxf(mloc, e);
    }
    mloc = fmaxf(mloc, __shfl_xor(mloc, 16));
    mloc = fmaxf(mloc, __shfl_xor(mloc, 32));
    __shared__ float sh[4];
    if ((t & 63) == 0) sh[t >> 6] = mloc;
    __syncthreads();
    if (t == 0)
        atomicMax(m_enc, fenc(fmaxf(fmaxf(sh[0], sh[1]), fmaxf(sh[2], sh[3]))));
}

// ---- Z reduce (grid-stride): w = exp(e - m) in place; 1 f64 atomic/block ----
__global__ void zred(float* __restrict__ ebuf, const unsigned* __restrict__ m_enc,
                     double* __restrict__ Z, int nE) {
    float m = fdec(*m_enc);
    int i0 = blockIdx.x * 256 + threadIdx.x;
    int stride = gridDim.x * 256;
    float sw = 0.f;
    for (int i = i0; i < nE; i += stride) {
        float w = expf(ebuf[i] - m);
        ebuf[i] = w;
        sw += w;
    }
    #pragma unroll
    for (int o = 32; o >= 1; o >>= 1) sw += __shfl_xor(sw, o);
    __shared__ float sh[4];
    if ((threadIdx.x & 63) == 0) sh[threadIdx.x >> 6] = sw;
    __syncthreads();
    if (threadIdx.x == 0) atomicAdd(Z, (double)(sh[0] + sh[1] + sh[2] + sh[3]));
}

// ---- gather-aggregate + elu + LayerNorm, one wave per node ----
__global__ void agg_ln(const float* __restrict__ Wh, const int* __restrict__ rowptr,
                       const int* __restrict__ csrs, const float* __restrict__ wbuf,
                       const double* __restrict__ Z, const float* __restrict__ g,
                       const float* __restrict__ b, float* __restrict__ out, int n) {
    int node = blockIdx.x * 4 + (threadIdx.x >> 6);
    int lane = threadIdx.x & 63;
    if (node >= n) return;
    float invZ = (float)(1.0 / Z[0]);
    int beg = rowptr[node], end = rowptr[node + 1];
    float acc = 0.f;
    for (int i = beg; i < end; i++) {
        int si = csrs[i];        // wave-uniform broadcast load
        float w = wbuf[i];       // wave-uniform broadcast load
        acc += w * Wh[(size_t)si * HID + lane];   // coalesced 256B row
    }
    float v = acc * invZ;
    v = v > 0.f ? v : expm1f(v);         // elu
    float s = v, s2 = v * v;
    #pragma unroll
    for (int o = 32; o >= 1; o >>= 1) {
        s += __shfl_xor(s, o);
        s2 += __shfl_xor(s2, o);
    }
    float mean = s * (1.f / 64.f);
    float var = s2 * (1.f / 64.f) - mean * mean;
    out[(size_t)node * HID + lane] = g[lane] * (v - mean) * rsqrtf(var + 1e-5f) + b[lane];
}

// ---- final: out = sigmoid(relu((sp+tp)@cW1+cb1)@cW2+cb2) ----
__global__ void final_kernel(const float* __restrict__ sp, const float* __restrict__ tp,
                             const float* __restrict__ cW1, const float* __restrict__ cb1,
                             const float* __restrict__ cW2, const float* __restrict__ cb2,
                             float* __restrict__ out, int n) {
    __shared__ float W1[64 * 32];
    __shared__ float W2[32];
    __shared__ float B1[32];
    __shared__ float hsh[8][64];
    int t = threadIdx.x;
    for (int i = t; i < 2048; i += 256) W1[i] = cW1[i];
    if (t < 32) { W2[t] = cW2[t]; B1[t] = cb1[t]; }
    __syncthreads();
    int ln = t >> 5;
    int j = t & 31;
    int node = blockIdx.x * 8 + ln;
    if (node < n) {
        hsh[ln][j]      = sp[(size_t)node * 64 + j]      + tp[(size_t)node * 64 + j];
        hsh[ln][j + 32] = sp[(size_t)node * 64 + j + 32] + tp[(size_t)node * 64 + j + 32];
    }
    __syncthreads();
    if (node >= n) return;
    float a = B1[j];
    #pragma unroll
    for (int k = 0; k < 64; k++) a += hsh[ln][k] * W1[k * 32 + j];
    a = fmaxf(a, 0.f);
    float p = a * W2[j];
    #pragma unroll
    for (int o = 16; o >= 1; o >>= 1) p += __shfl_xor(p, o, 32);
    if (j == 0) out[node] = 1.f / (1.f + expf(-(p + cb2[0])));
}

extern "C" void kernel_launch(void* const* d_in, const int* in_sizes, int n_in,
                              void* d_out, int out_size, void* d_ws, size_t ws_size,
                              hipStream_t stream) {
    const float* x   = (const float*)d_in[0];
    const int*   ei  = (const int*)d_in[1];
    const int*   tei = (const int*)d_in[3];
    const float* sW0 = (const float*)d_in[4],  *sa0 = (const float*)d_in[5];
    const float* sg0 = (const float*)d_in[6],  *sb0 = (const float*)d_in[7];
    const float* sW1 = (const float*)d_in[8],  *sa1 = (const float*)d_in[9];
    const float* sg1 = (const float*)d_in[10], *sb1 = (const float*)d_in[11];
    const float* tW0 = (const float*)d_in[12], *ta0 = (const float*)d_in[13];
    const float* tg0 = (const float*)d_in[14], *tb0 = (const float*)d_in[15];
    const float* tW1 = (const float*)d_in[16], *ta1 = (const float*)d_in[17];
    const float* tg1 = (const float*)d_in[18], *tb1 = (const float*)d_in[19];
    const float* cW1 = (const float*)d_in[20], *cb1 = (const float*)d_in[21];
    const float* cW2 = (const float*)d_in[22], *cb2 = (const float*)d_in[23];
    float* out = (float*)d_out;

    float* ws = (float*)d_ws;
    size_t o = 0;
    float* buf_h  = ws + o; o += (size_t)NN * HID;
    float* buf_Wh = ws + o; o += (size_t)NN * HID;
    float* buf_sp = ws + o; o += (size_t)NN * HID;
    float* ebuf   = ws + o; o += NE;
    double*   Zp    = (double*)(ws + o); o += 2;   // offset even -> 8B aligned
    float*    sum_a = ws + o; o += 1;
    unsigned* m_enc = (unsigned*)(ws + o); o += 1;
    int* ip = (int*)(ws + o);
    int* rowptrS = ip; ip += NN + 1;
    int* csrsS   = ip; ip += NE;
    int* cposS   = ip; ip += NE;
    int* rowptrT = ip; ip += NN + 1;
    int* csrsT   = ip; ip += NE;
    int* cposT   = ip; ip += NE;
    int* deg     = ip; ip += NN;    // reused as cursor
    int* rowtmp  = ip; ip += NN;
    int* bsum    = ip; ip += 256;

    const int NB_SCAN = (NN + 1023) / 1024;  // 98
    const int NB_EDGE = 2048;                // grid-stride edge kernels

    auto build_csr = [&](const int* src, const int* dst, int* rowptr, int* csrs, int* cpos) {
        hipMemsetAsync(deg, 0, NN * sizeof(int), stream);
        hist_k<<<(NE + 255) / 256, 256, 0, stream>>>(dst, deg, NE);
        scanA<<<NB_SCAN, 256, 0, stream>>>(deg, rowtmp, bsum, NN);
        scanB<<<1, 256, 0, stream>>>(bsum, NB_SCAN);
        scanC<<<(NN + 1 + 255) / 256, 256, 0, stream>>>(rowtmp, bsum, rowptr, NN, NE);
        hipMemcpyAsync(deg, rowptr, NN * sizeof(int), hipMemcpyDeviceToDevice, stream);
        csr_fill<<<(NE + 255) / 256, 256, 0, stream>>>(src, dst, deg, csrs, cpos, NE);
    };

    build_csr(ei,  ei  + NE, rowptrS, csrsS, cposS);
    build_csr(tei, tei + NE, rowptrT, csrsT, cposT);

    auto run_layer = [&](const float* hin, int K, const float* W, const float* a,
                         const float* g, const float* b, const int* src, const int* dst,
                         const int* rowptr, const int* csrs, const int* cpos, float* hout) {
        prep_kernel<<<1, 128, 0, stream>>>(a, sum_a, m_enc, Zp);
        if (K == 8)
            gemm_k<8><<<(NN + 63) / 64, 256, 0, stream>>>(hin, W, buf_Wh, NN);
        else
            gemm_k<64><<<(NN + 63) / 64, 256, 0, stream>>>(hin, W, buf_Wh, NN);
        edge_pass1<<<NB_EDGE, 256, 0, stream>>>(buf_Wh, src, dst, sum_a, cpos, ebuf, m_enc, NE);
        zred<<<NB_EDGE, 256, 0, stream>>>(ebuf, m_enc, Zp, NE);
        agg_ln<<<(NN + 3) / 4, 256, 0, stream>>>(buf_Wh, rowptr, csrs, ebuf, Zp, g, b, hout, NN);
    };

    // spatial stack
    run_layer(x,     8,  sW0, sa0, sg0, sb0, ei, ei + NE, rowptrS, csrsS, cposS, buf_h);
    run_layer(buf_h, 64, sW1, sa1, sg1, sb1, ei, ei + NE, rowptrS, csrsS, cposS, buf_sp);
    // temporal stack
    run_layer(x,     8,  tW0, ta0, tg0, tb0, tei, tei + NE, rowptrT, csrsT, cposT, buf_h);
    run_layer(buf_h, 64, tW1, ta1, tg1, tb1, tei, tei + NE, rowptrT, csrsT, cposT, buf_h);

    final_kernel<<<(NN + 7) / 8, 256, 0, stream>>>(buf_sp, buf_h, cW1, cb1, cW2, cb2, out, NN);
}

// Round 4
// 1501.190 us; speedup vs baseline: 26.2630x; 1.1893x over previous
//
#include <hip/hip_runtime.h>
#include <math.h>

#define NN 100000
#define NE 1600000
#define HID 64
#define NB_EDGE 2048

// ---- per-layer prep: sum(a) scalar ----
__global__ void prep_kernel(const float* __restrict__ a, float* __restrict__ sum_a) {
    int t = threadIdx.x; // 128 threads, a has 2*HID=128 elems
    float v = a[t];
    #pragma unroll
    for (int o = 32; o >= 1; o >>= 1) v += __shfl_xor(v, o);
    __shared__ float sh[2];
    if ((t & 63) == 0) sh[t >> 6] = v;
    __syncthreads();
    if (t == 0) *sum_a = sh[0] + sh[1];
}

// ================= CSR build =================
__global__ void hist_k(const int* __restrict__ dst, int* __restrict__ deg, int nE) {
    int e = blockIdx.x * 256 + threadIdx.x;
    if (e < nE) atomicAdd(&deg[dst[e]], 1);
}

__global__ void scanA(const int* __restrict__ deg, int* __restrict__ rowtmp,
                      int* __restrict__ bsum, int n) {
    __shared__ int sh[256];
    int t = threadIdx.x;
    int base = blockIdx.x * 1024 + t * 4;
    int a0 = (base + 0 < n) ? deg[base + 0] : 0;
    int a1 = (base + 1 < n) ? deg[base + 1] : 0;
    int a2 = (base + 2 < n) ? deg[base + 2] : 0;
    int a3 = (base + 3 < n) ? deg[base + 3] : 0;
    int s = a0 + a1 + a2 + a3;
    sh[t] = s;
    __syncthreads();
    for (int off = 1; off < 256; off <<= 1) {
        int x = (t >= off) ? sh[t - off] : 0;
        __syncthreads();
        sh[t] += x;
        __syncthreads();
    }
    int excl = sh[t] - s;
    if (t == 255) bsum[blockIdx.x] = sh[255];
    if (base + 0 < n) rowtmp[base + 0] = excl;
    if (base + 1 < n) rowtmp[base + 1] = excl + a0;
    if (base + 2 < n) rowtmp[base + 2] = excl + a0 + a1;
    if (base + 3 < n) rowtmp[base + 3] = excl + a0 + a1 + a2;
}

__global__ void scanB(int* __restrict__ bsum, int nb) {
    __shared__ int sh[256];
    int t = threadIdx.x;
    int v = (t < nb) ? bsum[t] : 0;
    sh[t] = v;
    __syncthreads();
    for (int off = 1; off < 256; off <<= 1) {
        int x = (t >= off) ? sh[t - off] : 0;
        __syncthreads();
        sh[t] += x;
        __syncthreads();
    }
    if (t < nb) bsum[t] = sh[t] - v; // exclusive
}

__global__ void scanC(const int* __restrict__ rowtmp, const int* __restrict__ bsum,
                      int* __restrict__ rowptr, int n, int total) {
    int i = blockIdx.x * 256 + threadIdx.x;
    if (i < n) rowptr[i] = rowtmp[i] + bsum[i >> 10];
    if (i == n) rowptr[n] = total;
}

__global__ void csr_fill(const int* __restrict__ src, const int* __restrict__ dst,
                         int* __restrict__ cursor, int* __restrict__ csrs, int nE) {
    int e = blockIdx.x * 256 + threadIdx.x;
    if (e >= nE) return;
    int p = atomicAdd(&cursor[dst[e]], 1);
    csrs[p] = src[e];
}

// ---- GEMM: Wh[n][64] = h[n][K] @ W[K][64] ----
template <int K>
__global__ void gemm_k(const float* __restrict__ h, const float* __restrict__ W,
                       float* __restrict__ Wh, int n) {
    __shared__ float Wl[K][HID];
    int t = threadIdx.x;
    for (int i = t; i < K * HID; i += 256) Wl[i / HID][i % HID] = W[i];
    __syncthreads();
    int node = blockIdx.x * 64 + (t >> 2);
    int c0 = (t & 3) * 16;
    if (node >= n) return;
    float acc[16];
    #pragma unroll
    for (int j = 0; j < 16; j++) acc[j] = 0.f;
    const float* hr = h + (size_t)node * K;
    #pragma unroll
    for (int k = 0; k < K; k++) {
        float v = hr[k];
        #pragma unroll
        for (int j = 0; j < 16; j++) acc[j] += v * Wl[k][c0 + j];
    }
    float* o = Wh + (size_t)node * HID + c0;
    #pragma unroll
    for (int j = 0; j < 16; j += 4)
        *(float4*)(o + j) = make_float4(acc[j], acc[j+1], acc[j+2], acc[j+3]);
}

// ---- pass 1: node-parallel score scan, online (max, Z) per block ----
__global__ void edge_score(const float* __restrict__ Wh, const int* __restrict__ rowptr,
                           const int* __restrict__ csrs, const float* __restrict__ sum_a,
                           float* __restrict__ bmax, float* __restrict__ bsumz, int n) {
    int t = threadIdx.x;
    int w = t >> 6, lane = t & 63;
    float sa = *sum_a;
    float m = -INFINITY, z = 0.f;
    for (int node = blockIdx.x * 4 + w; node < n; node += NB_EDGE * 4) {
        float q = Wh[(size_t)node * HID + lane];
        int beg = rowptr[node], end = rowptr[node + 1];
        int i = beg;
        for (; i + 4 <= end; i += 4) {
            int s0 = csrs[i], s1 = csrs[i + 1], s2 = csrs[i + 2], s3 = csrs[i + 3];
            float v0 = Wh[(size_t)s0 * HID + lane];
            float v1 = Wh[(size_t)s1 * HID + lane];
            float v2 = Wh[(size_t)s2 * HID + lane];
            float v3 = Wh[(size_t)s3 * HID + lane];
            float x0 = q * v0, x1 = q * v1, x2 = q * v2, x3 = q * v3;
            #pragma unroll
            for (int o = 32; o >= 1; o >>= 1) {
                x0 += __shfl_xor(x0, o); x1 += __shfl_xor(x1, o);
                x2 += __shfl_xor(x2, o); x3 += __shfl_xor(x3, o);
            }
            float e0 = x0 * sa; e0 = e0 > 0.f ? e0 : 0.2f * e0;
            float e1 = x1 * sa; e1 = e1 > 0.f ? e1 : 0.2f * e1;
            float e2 = x2 * sa; e2 = e2 > 0.f ? e2 : 0.2f * e2;
            float e3 = x3 * sa; e3 = e3 > 0.f ? e3 : 0.2f * e3;
            float en = fmaxf(fmaxf(e0, e1), fmaxf(e2, e3));
            if (en > m) { z *= __expf(m - en); m = en; }
            z += __expf(e0 - m) + __expf(e1 - m) + __expf(e2 - m) + __expf(e3 - m);
        }
        for (; i < end; i++) {
            float x0 = q * Wh[(size_t)csrs[i] * HID + lane];
            #pragma unroll
            for (int o = 32; o >= 1; o >>= 1) x0 += __shfl_xor(x0, o);
            float e0 = x0 * sa; e0 = e0 > 0.f ? e0 : 0.2f * e0;
            if (e0 > m) { z *= __expf(m - e0); m = e0; }
            z += __expf(e0 - m);
        }
    }
    __shared__ float shm[4], shz[4];
    if (lane == 0) { shm[w] = m; shz[w] = z; }
    __syncthreads();
    if (t == 0) {
        float M = shm[0], Zz = shz[0];
        #pragma unroll
        for (int k = 1; k < 4; k++) {
            float m2 = shm[k], z2 = shz[k];
            float mn = fmaxf(M, m2);
            float f1 = (M == -INFINITY) ? 0.f : __expf(M - mn);
            float f2 = (m2 == -INFINITY) ? 0.f : __expf(m2 - mn);
            Zz = Zz * f1 + z2 * f2; M = mn;
        }
        bmax[blockIdx.x] = M; bsumz[blockIdx.x] = Zz;
    }
}

// ---- combine 2048 block aggregates -> global m, 1/Z ----
__global__ void combine_k(const float* __restrict__ bmax, const float* __restrict__ bsumz,
                          float* __restrict__ mz, int nb) {
    int t = threadIdx.x; // 256
    float m = -INFINITY;
    for (int i = t; i < nb; i += 256) m = fmaxf(m, bmax[i]);
    #pragma unroll
    for (int o = 32; o >= 1; o >>= 1) m = fmaxf(m, __shfl_xor(m, o));
    __shared__ float sm[4];
    if ((t & 63) == 0) sm[t >> 6] = m;
    __syncthreads();
    m = fmaxf(fmaxf(sm[0], sm[1]), fmaxf(sm[2], sm[3]));
    double z = 0.0;
    for (int i = t; i < nb; i += 256)
        z += (double)bsumz[i] * exp((double)bmax[i] - (double)m);
    #pragma unroll
    for (int o = 32; o >= 1; o >>= 1) z += __shfl_xor(z, o);
    __shared__ double sz[4];
    if ((t & 63) == 0) sz[t >> 6] = z;
    __syncthreads();
    if (t == 0) { mz[0] = m; mz[1] = (float)(1.0 / (sz[0] + sz[1] + sz[2] + sz[3])); }
}

// ---- pass 2: recompute scores, aggregate, elu + LayerNorm ----
__global__ void agg_ln(const float* __restrict__ Wh, const int* __restrict__ rowptr,
                       const int* __restrict__ csrs, const float* __restrict__ sum_a,
                       const float* __restrict__ mz, const float* __restrict__ g,
                       const float* __restrict__ b, float* __restrict__ out, int n) {
    int node = blockIdx.x * 4 + (threadIdx.x >> 6);
    int lane = threadIdx.x & 63;
    if (node >= n) return;
    float sa = *sum_a;
    float m = mz[0], invZ = mz[1];
    float q = Wh[(size_t)node * HID + lane];
    int beg = rowptr[node], end = rowptr[node + 1];
    float a0 = 0.f, a1 = 0.f, a2 = 0.f, a3 = 0.f;
    int i = beg;
    for (; i + 4 <= end; i += 4) {
        int s0 = csrs[i], s1 = csrs[i + 1], s2 = csrs[i + 2], s3 = csrs[i + 3];
        float v0 = Wh[(size_t)s0 * HID + lane];
        float v1 = Wh[(size_t)s1 * HID + lane];
        float v2 = Wh[(size_t)s2 * HID + lane];
        float v3 = Wh[(size_t)s3 * HID + lane];
        float x0 = q * v0, x1 = q * v1, x2 = q * v2, x3 = q * v3;
        #pragma unroll
        for (int o = 32; o >= 1; o >>= 1) {
            x0 += __shfl_xor(x0, o); x1 += __shfl_xor(x1, o);
            x2 += __shfl_xor(x2, o); x3 += __shfl_xor(x3, o);
        }
        float e0 = x0 * sa; e0 = e0 > 0.f ? e0 : 0.2f * e0;
        float e1 = x1 * sa; e1 = e1 > 0.f ? e1 : 0.2f * e1;
        float e2 = x2 * sa; e2 = e2 > 0.f ? e2 : 0.2f * e2;
        float e3 = x3 * sa; e3 = e3 > 0.f ? e3 : 0.2f * e3;
        a0 += __expf(e0 - m) * v0;
        a1 += __expf(e1 - m) * v1;
        a2 += __expf(e2 - m) * v2;
        a3 += __expf(e3 - m) * v3;
    }
    for (; i < end; i++) {
        float v0 = Wh[(size_t)csrs[i] * HID + lane];
        float x0 = q * v0;
        #pragma unroll
        for (int o = 32; o >= 1; o >>= 1) x0 += __shfl_xor(x0, o);
        float e0 = x0 * sa; e0 = e0 > 0.f ? e0 : 0.2f * e0;
        a0 += __expf(e0 - m) * v0;
    }
    float v = ((a0 + a1) + (a2 + a3)) * invZ;
    v = v > 0.f ? v : expm1f(v);         // elu
    float s = v, s2 = v * v;
    #pragma unroll
    for (int o = 32; o >= 1; o >>= 1) {
        s += __shfl_xor(s, o);
        s2 += __shfl_xor(s2, o);
    }
    float mean = s * (1.f / 64.f);
    float var = s2 * (1.f / 64.f) - mean * mean;
    out[(size_t)node * HID + lane] = g[lane] * (v - mean) * rsqrtf(var + 1e-5f) + b[lane];
}

// ---- final: out = sigmoid(relu((sp+tp)@cW1+cb1)@cW2+cb2) ----
__global__ void final_kernel(const float* __restrict__ sp, const float* __restrict__ tp,
                             const float* __restrict__ cW1, const float* __restrict__ cb1,
                             const float* __restrict__ cW2, const float* __restrict__ cb2,
                             float* __restrict__ out, int n) {
    __shared__ float W1[64 * 32];
    __shared__ float W2[32];
    __shared__ float B1[32];
    __shared__ float hsh[8][64];
    int t = threadIdx.x;
    for (int i = t; i < 2048; i += 256) W1[i] = cW1[i];
    if (t < 32) { W2[t] = cW2[t]; B1[t] = cb1[t]; }
    __syncthreads();
    int ln = t >> 5;
    int j = t & 31;
    int node = blockIdx.x * 8 + ln;
    if (node < n) {
        hsh[ln][j]      = sp[(size_t)node * 64 + j]      + tp[(size_t)node * 64 + j];
        hsh[ln][j + 32] = sp[(size_t)node * 64 + j + 32] + tp[(size_t)node * 64 + j + 32];
    }
    __syncthreads();
    if (node >= n) return;
    float a = B1[j];
    #pragma unroll
    for (int k = 0; k < 64; k++) a += hsh[ln][k] * W1[k * 32 + j];
    a = fmaxf(a, 0.f);
    float p = a * W2[j];
    #pragma unroll
    for (int o = 16; o >= 1; o >>= 1) p += __shfl_xor(p, o, 32);
    if (j == 0) out[node] = 1.f / (1.f + expf(-(p + cb2[0])));
}

extern "C" void kernel_launch(void* const* d_in, const int* in_sizes, int n_in,
                              void* d_out, int out_size, void* d_ws, size_t ws_size,
                              hipStream_t stream) {
    const float* x   = (const float*)d_in[0];
    const int*   ei  = (const int*)d_in[1];
    const int*   tei = (const int*)d_in[3];
    const float* sW0 = (const float*)d_in[4],  *sa0 = (const float*)d_in[5];
    const float* sg0 = (const float*)d_in[6],  *sb0 = (const float*)d_in[7];
    const float* sW1 = (const float*)d_in[8],  *sa1 = (const float*)d_in[9];
    const float* sg1 = (const float*)d_in[10], *sb1 = (const float*)d_in[11];
    const float* tW0 = (const float*)d_in[12], *ta0 = (const float*)d_in[13];
    const float* tg0 = (const float*)d_in[14], *tb0 = (const float*)d_in[15];
    const float* tW1 = (const float*)d_in[16], *ta1 = (const float*)d_in[17];
    const float* tg1 = (const float*)d_in[18], *tb1 = (const float*)d_in[19];
    const float* cW1 = (const float*)d_in[20], *cb1 = (const float*)d_in[21];
    const float* cW2 = (const float*)d_in[22], *cb2 = (const float*)d_in[23];
    float* out = (float*)d_out;

    float* ws = (float*)d_ws;
    size_t o = 0;
    float* buf_h  = ws + o; o += (size_t)NN * HID;
    float* buf_Wh = ws + o; o += (size_t)NN * HID;
    float* buf_sp = ws + o; o += (size_t)NN * HID;
    float* bmax   = ws + o; o += NB_EDGE;
    float* bsumz  = ws + o; o += NB_EDGE;
    float* sum_a  = ws + o; o += 1;
    float* mz     = ws + o; o += 3;     // 2 used, keep int area 4B aligned
    int* ip = (int*)(ws + o);
    int* rowptrS = ip; ip += NN + 1;
    int* csrsS   = ip; ip += NE;
    int* rowptrT = ip; ip += NN + 1;
    int* csrsT   = ip; ip += NE;
    int* deg     = ip; ip += NN;    // reused as cursor
    int* rowtmp  = ip; ip += NN;
    int* bsum    = ip; ip += 256;

    const int NB_SCAN = (NN + 1023) / 1024;  // 98

    auto build_csr = [&](const int* src, const int* dst, int* rowptr, int* csrs) {
        hipMemsetAsync(deg, 0, NN * sizeof(int), stream);
        hist_k<<<(NE + 255) / 256, 256, 0, stream>>>(dst, deg, NE);
        scanA<<<NB_SCAN, 256, 0, stream>>>(deg, rowtmp, bsum, NN);
        scanB<<<1, 256, 0, stream>>>(bsum, NB_SCAN);
        scanC<<<(NN + 1 + 255) / 256, 256, 0, stream>>>(rowtmp, bsum, rowptr, NN, NE);
        hipMemcpyAsync(deg, rowptr, NN * sizeof(int), hipMemcpyDeviceToDevice, stream);
        csr_fill<<<(NE + 255) / 256, 256, 0, stream>>>(src, dst, deg, csrs, NE);
    };

    build_csr(ei,  ei  + NE, rowptrS, csrsS);
    build_csr(tei, tei + NE, rowptrT, csrsT);

    auto run_layer = [&](const float* hin, int K, const float* W, const float* a,
                         const float* g, const float* b,
                         const int* rowptr, const int* csrs, float* hout) {
        prep_kernel<<<1, 128, 0, stream>>>(a, sum_a);
        if (K == 8)
            gemm_k<8><<<(NN + 63) / 64, 256, 0, stream>>>(hin, W, buf_Wh, NN);
        else
            gemm_k<64><<<(NN + 63) / 64, 256, 0, stream>>>(hin, W, buf_Wh, NN);
        edge_score<<<NB_EDGE, 256, 0, stream>>>(buf_Wh, rowptr, csrs, sum_a, bmax, bsumz, NN);
        combine_k<<<1, 256, 0, stream>>>(bmax, bsumz, mz, NB_EDGE);
        agg_ln<<<(NN + 3) / 4, 256, 0, stream>>>(buf_Wh, rowptr, csrs, sum_a, mz, g, b, hout, NN);
    };

    // spatial stack
    run_layer(x,     8,  sW0, sa0, sg0, sb0, rowptrS, csrsS, buf_h);
    run_layer(buf_h, 64, sW1, sa1, sg1, sb1, rowptrS, csrsS, buf_sp);
    // temporal stack
    run_layer(x,     8,  tW0, ta0, tg0, tb0, rowptrT, csrsT, buf_h);
    run_layer(buf_h, 64, tW1, ta1, tg1, tb1, rowptrT, csrsT, buf_h);

    final_kernel<<<(NN + 7) / 8, 256, 0, stream>>>(buf_sp, buf_h, cW1, cb1, cW2, cb2, out, NN);
}

// Round 5
// 900.398 us; speedup vs baseline: 43.7871x; 1.6673x over previous
//
#include <hip/hip_runtime.h>
#include <math.h>

#define NN 100000
#define NE 1600000
#define HID 64
#define NBE 2048                 // grid for edge_agg
#define NBH 6250                 // (NE+255)/256

// online-softmax merge: (m,z) <- (m,z) (+) (m2,z2); nan-safe for -inf states
__device__ __forceinline__ void smerge(float& m, float& z, float m2, float z2) {
    if (m2 > m) { z = z * __expf(m - m2) + z2; m = m2; }
    else if (m2 > -INFINITY) { z += z2 * __expf(m2 - m); }
}

// ---- all four sum(a) scalars in one launch ----
__global__ void prep4(const float* __restrict__ a0, const float* __restrict__ a1,
                      const float* __restrict__ a2, const float* __restrict__ a3,
                      float* __restrict__ sum_a) {
    int w = threadIdx.x >> 6, lane = threadIdx.x & 63;
    const float* a = (w == 0) ? a0 : (w == 1) ? a1 : (w == 2) ? a2 : a3;
    float v = a[lane] + a[lane + 64];
    #pragma unroll
    for (int o = 32; o >= 1; o >>= 1) v += __shfl_xor(v, o);
    if (lane == 0) sum_a[w] = v;
}

// ================= CSR build (S and T fused via side-select) =================
__global__ void hist2(const int* __restrict__ eiS, const int* __restrict__ eiT,
                      int* __restrict__ degS, int* __restrict__ degT) {
    int side = blockIdx.x >= NBH;
    int e = (blockIdx.x - side * NBH) * 256 + threadIdx.x;
    if (e >= NE) return;
    const int* dst = (side ? eiT : eiS) + NE;
    atomicAdd((side ? degT : degS) + dst[e], 1);
}

__global__ void scanA(const int* __restrict__ deg, int* __restrict__ rowtmp,
                      int* __restrict__ bsum, int n) {
    __shared__ int sh[256];
    int t = threadIdx.x;
    int base = blockIdx.x * 1024 + t * 4;
    int a0 = (base + 0 < n) ? deg[base + 0] : 0;
    int a1 = (base + 1 < n) ? deg[base + 1] : 0;
    int a2 = (base + 2 < n) ? deg[base + 2] : 0;
    int a3 = (base + 3 < n) ? deg[base + 3] : 0;
    int s = a0 + a1 + a2 + a3;
    sh[t] = s;
    __syncthreads();
    for (int off = 1; off < 256; off <<= 1) {
        int x = (t >= off) ? sh[t - off] : 0;
        __syncthreads();
        sh[t] += x;
        __syncthreads();
    }
    int excl = sh[t] - s;
    if (t == 255) bsum[blockIdx.x] = sh[255];
    if (base + 0 < n) rowtmp[base + 0] = excl;
    if (base + 1 < n) rowtmp[base + 1] = excl + a0;
    if (base + 2 < n) rowtmp[base + 2] = excl + a0 + a1;
    if (base + 3 < n) rowtmp[base + 3] = excl + a0 + a1 + a2;
}

__global__ void scanB(int* __restrict__ bsum, int nb) {
    __shared__ int sh[256];
    int t = threadIdx.x;
    int v = (t < nb) ? bsum[t] : 0;
    sh[t] = v;
    __syncthreads();
    for (int off = 1; off < 256; off <<= 1) {
        int x = (t >= off) ? sh[t - off] : 0;
        __syncthreads();
        sh[t] += x;
        __syncthreads();
    }
    if (t < nb) bsum[t] = sh[t] - v; // exclusive
}

__global__ void scanC(const int* __restrict__ rowtmp, const int* __restrict__ bsum,
                      int* __restrict__ rowptr, int n, int total) {
    int i = blockIdx.x * 256 + threadIdx.x;
    if (i < n) rowptr[i] = rowtmp[i] + bsum[i >> 10];
    if (i == n) rowptr[n] = total;
}

__global__ void cpy2(const int* __restrict__ rpS, const int* __restrict__ rpT,
                     int* __restrict__ curS, int* __restrict__ curT, int n) {
    int i = blockIdx.x * 256 + threadIdx.x;
    if (i < n) { curS[i] = rpS[i]; curT[i] = rpT[i]; }
}

__global__ void fill2(const int* __restrict__ eiS, const int* __restrict__ eiT,
                      int* __restrict__ curS, int* __restrict__ curT,
                      int* __restrict__ csrsS, int* __restrict__ csrsT) {
    int side = blockIdx.x >= NBH;
    int e = (blockIdx.x - side * NBH) * 256 + threadIdx.x;
    if (e >= NE) return;
    const int* ei = side ? eiT : eiS;
    int p = atomicAdd((side ? curT : curS) + ei[NE + e], 1);
    (side ? csrsT : csrsS)[p] = ei[e];
}

// ---- GEMM: Wh[n][64] = h[n][K] @ W[K][64], float4 loads ----
template <int K>
__global__ void gemm_k(const float* __restrict__ h, const float* __restrict__ W,
                       float* __restrict__ Wh, int n) {
    __shared__ float Wl[K][HID];
    int t = threadIdx.x;
    for (int i = t; i < K * HID / 4; i += 256)
        ((float4*)Wl)[i] = ((const float4*)W)[i];
    __syncthreads();
    int node = blockIdx.x * 64 + (t >> 2);
    int c0 = (t & 3) * 16;
    if (node >= n) return;
    float acc[16];
    #pragma unroll
    for (int j = 0; j < 16; j++) acc[j] = 0.f;
    const float* hr = h + (size_t)node * K;
    #pragma unroll
    for (int k4 = 0; k4 < K / 4; k4++) {
        float4 hv = *(const float4*)(hr + k4 * 4);
        #pragma unroll
        for (int j = 0; j < 16; j++)
            acc[j] += hv.x * Wl[k4*4+0][c0+j] + hv.y * Wl[k4*4+1][c0+j]
                    + hv.z * Wl[k4*4+2][c0+j] + hv.w * Wl[k4*4+3][c0+j];
    }
    float* o = Wh + (size_t)node * HID + c0;
    #pragma unroll
    for (int j = 0; j < 16; j += 4)
        *(float4*)(o + j) = make_float4(acc[j], acc[j+1], acc[j+2], acc[j+3]);
}

// ---- single edge pass: online-softmax aggregate per node ----
// lane layout: 4 groups of 16 lanes; group g handles edge i+g, lane holds 4 dims.
__global__ void edge_agg(const float* __restrict__ Wh, const int* __restrict__ rowptr,
                         const int* __restrict__ csrs, const float* __restrict__ sum_a_p,
                         float* __restrict__ acc, float* __restrict__ mloc,
                         float* __restrict__ bmax, float* __restrict__ bsumz, int n) {
    int t = threadIdx.x;
    int w = t >> 6, lane = t & 63;
    int g = lane >> 4, l16 = lane & 15;
    float sa = *sum_a_p;
    float M = -INFINITY, Z = 0.f;                 // per-wave running block aggregate
    for (int node = blockIdx.x * 4 + w; node < n; node += NBE * 4) {
        float4 q4 = *(const float4*)(Wh + (size_t)node * HID + l16 * 4);
        int beg = rowptr[node], end = rowptr[node + 1];
        float m = -INFINITY, z = 0.f;
        float4 a4 = make_float4(0.f, 0.f, 0.f, 0.f);
        for (int i = beg; i < end; i += 4) {
            int idx = i + g;
            bool act = idx < end;
            int s = csrs[act ? idx : beg];
            float4 v4 = *(const float4*)(Wh + (size_t)s * HID + l16 * 4);
            float x = q4.x*v4.x + q4.y*v4.y + q4.z*v4.z + q4.w*v4.w;
            x += __shfl_xor(x, 1); x += __shfl_xor(x, 2);
            x += __shfl_xor(x, 4); x += __shfl_xor(x, 8);
            float e = x * sa;
            e = e > 0.f ? e : 0.2f * e;           // leaky_relu 0.2
            if (act) {
                if (e > m) {
                    float f = __expf(m - e);      // m=-inf -> 0, no nan
                    z *= f; a4.x *= f; a4.y *= f; a4.z *= f; a4.w *= f;
                    m = e;
                }
                float wgt = __expf(e - m);
                z += wgt;
                a4.x += wgt * v4.x; a4.y += wgt * v4.y;
                a4.z += wgt * v4.z; a4.w += wgt * v4.w;
            }
        }
        // merge the 4 groups' (m, z, acc4) via butterfly xor 16, 32
        #pragma unroll
        for (int o = 16; o <= 32; o <<= 1) {
            float mo = __shfl_xor(m, o), zo = __shfl_xor(z, o);
            float ax = __shfl_xor(a4.x, o), ay = __shfl_xor(a4.y, o);
            float az = __shfl_xor(a4.z, o), aw = __shfl_xor(a4.w, o);
            float mn = fmaxf(m, mo);
            float fs = (m  > -INFINITY) ? __expf(m  - mn) : 0.f;
            float fo = (mo > -INFINITY) ? __expf(mo - mn) : 0.f;
            z = z * fs + zo * fo;
            a4.x = a4.x*fs + ax*fo; a4.y = a4.y*fs + ay*fo;
            a4.z = a4.z*fs + az*fo; a4.w = a4.w*fs + aw*fo;
            m = mn;
        }
        if (g == 0) {
            *(float4*)(acc + (size_t)node * HID + l16 * 4) = a4;
            if (l16 == 0) mloc[node] = m;
        }
        smerge(M, Z, m, z);
    }
    __shared__ float shm[4], shz[4];
    if (lane == 0) { shm[w] = M; shz[w] = Z; }
    __syncthreads();
    if (t == 0) {
        float Mb = shm[0], Zb = shz[0];
        #pragma unroll
        for (int k = 1; k < 4; k++) smerge(Mb, Zb, shm[k], shz[k]);
        bmax[blockIdx.x] = Mb; bsumz[blockIdx.x] = Zb;
    }
}

// ---- combine 2048 block aggregates -> global m, 1/Z ----
__global__ void combine_k(const float* __restrict__ bmax, const float* __restrict__ bsumz,
                          float* __restrict__ mz, int nb) {
    int t = threadIdx.x; // 256
    float m = -INFINITY;
    for (int i = t; i < nb; i += 256) m = fmaxf(m, bmax[i]);
    #pragma unroll
    for (int o = 32; o >= 1; o >>= 1) m = fmaxf(m, __shfl_xor(m, o));
    __shared__ float sm[4];
    if ((t & 63) == 0) sm[t >> 6] = m;
    __syncthreads();
    m = fmaxf(fmaxf(sm[0], sm[1]), fmaxf(sm[2], sm[3]));
    double z = 0.0;
    for (int i = t; i < nb; i += 256) {
        float bm = bmax[i];
        if (bm > -INFINITY) z += (double)bsumz[i] * exp((double)bm - (double)m);
    }
    #pragma unroll
    for (int o = 32; o >= 1; o >>= 1) z += __shfl_xor(z, o);
    __shared__ double sz[4];
    if ((t & 63) == 0) sz[t >> 6] = z;
    __syncthreads();
    if (t == 0) { mz[0] = m; mz[1] = (float)(1.0 / (sz[0] + sz[1] + sz[2] + sz[3])); }
}

// ---- streaming normalize + elu + LayerNorm (safe in-place: acc may == out) ----
__global__ void norm_ln(const float* __restrict__ acc, const float* __restrict__ mloc,
                        const float* __restrict__ mz, const float* __restrict__ g,
                        const float* __restrict__ b, float* __restrict__ out, int n) {
    int node = blockIdx.x * 4 + (threadIdx.x >> 6);
    int lane = threadIdx.x & 63;
    if (node >= n) return;
    float scale = __expf(mloc[node] - mz[0]) * mz[1];   // mloc=-inf -> 0
    float v = acc[(size_t)node * HID + lane] * scale;
    v = v > 0.f ? v : expm1f(v);         // elu
    float s = v, s2 = v * v;
    #pragma unroll
    for (int o = 32; o >= 1; o >>= 1) {
        s += __shfl_xor(s, o);
        s2 += __shfl_xor(s2, o);
    }
    float mean = s * (1.f / 64.f);
    float var = s2 * (1.f / 64.f) - mean * mean;
    out[(size_t)node * HID + lane] = g[lane] * (v - mean) * rsqrtf(var + 1e-5f) + b[lane];
}

// ---- final: out = sigmoid(relu((sp+tp)@cW1+cb1)@cW2+cb2) ----
__global__ void final_kernel(const float* __restrict__ sp, const float* __restrict__ tp,
                             const float* __restrict__ cW1, const float* __restrict__ cb1,
                             const float* __restrict__ cW2, const float* __restrict__ cb2,
                             float* __restrict__ out, int n) {
    __shared__ float W1[64 * 32];
    __shared__ float W2[32];
    __shared__ float B1[32];
    __shared__ float hsh[8][64];
    int t = threadIdx.x;
    for (int i = t; i < 2048; i += 256) W1[i] = cW1[i];
    if (t < 32) { W2[t] = cW2[t]; B1[t] = cb1[t]; }
    __syncthreads();
    int ln = t >> 5;
    int j = t & 31;
    int node = blockIdx.x * 8 + ln;
    if (node < n) {
        hsh[ln][j]      = sp[(size_t)node * 64 + j]      + tp[(size_t)node * 64 + j];
        hsh[ln][j + 32] = sp[(size_t)node * 64 + j + 32] + tp[(size_t)node * 64 + j + 32];
    }
    __syncthreads();
    if (node >= n) return;
    float a = B1[j];
    #pragma unroll
    for (int k = 0; k < 64; k++) a += hsh[ln][k] * W1[k * 32 + j];
    a = fmaxf(a, 0.f);
    float p = a * W2[j];
    #pragma unroll
    for (int o = 16; o >= 1; o >>= 1) p += __shfl_xor(p, o, 32);
    if (j == 0) out[node] = 1.f / (1.f + expf(-(p + cb2[0])));
}

extern "C" void kernel_launch(void* const* d_in, const int* in_sizes, int n_in,
                              void* d_out, int out_size, void* d_ws, size_t ws_size,
                              hipStream_t stream) {
    const float* x   = (const float*)d_in[0];
    const int*   ei  = (const int*)d_in[1];
    const int*   tei = (const int*)d_in[3];
    const float* sW0 = (const float*)d_in[4],  *sa0 = (const float*)d_in[5];
    const float* sg0 = (const float*)d_in[6],  *sb0 = (const float*)d_in[7];
    const float* sW1 = (const float*)d_in[8],  *sa1 = (const float*)d_in[9];
    const float* sg1 = (const float*)d_in[10], *sb1 = (const float*)d_in[11];
    const float* tW0 = (const float*)d_in[12], *ta0 = (const float*)d_in[13];
    const float* tg0 = (const float*)d_in[14], *tb0 = (const float*)d_in[15];
    const float* tW1 = (const float*)d_in[16], *ta1 = (const float*)d_in[17];
    const float* tg1 = (const float*)d_in[18], *tb1 = (const float*)d_in[19];
    const float* cW1 = (const float*)d_in[20], *cb1 = (const float*)d_in[21];
    const float* cW2 = (const float*)d_in[22], *cb2 = (const float*)d_in[23];
    float* out = (float*)d_out;

    float* ws = (float*)d_ws;
    size_t o = 0;
    float* buf_h  = ws + o; o += (size_t)NN * HID;   // h / acc (aliased)
    float* buf_Wh = ws + o; o += (size_t)NN * HID;
    float* buf_sp = ws + o; o += (size_t)NN * HID;
    float* mloc   = ws + o; o += NN;
    float* bmax   = ws + o; o += NBE;
    float* bsumz  = ws + o; o += NBE;
    float* sum_a  = ws + o; o += 4;
    float* mz     = ws + o; o += 4;
    int* ip = (int*)(ws + o);
    int* rowptrS = ip; ip += NN + 1;
    int* rowptrT = ip; ip += NN + 1;
    int* csrsS   = ip; ip += NE;
    int* csrsT   = ip; ip += NE;
    int* degS    = ip; ip += NN;   // contiguous with degT for single memset; reused as cursors
    int* degT    = ip; ip += NN;
    int* rowtmp  = ip; ip += NN;
    int* bsum    = ip; ip += 256;

    const int NBS = (NN + 1023) / 1024;  // 98

    // ---- CSR build (both edge lists) ----
    hipMemsetAsync(degS, 0, 2 * NN * sizeof(int), stream);
    hist2<<<2 * NBH, 256, 0, stream>>>(ei, tei, degS, degT);
    scanA<<<NBS, 256, 0, stream>>>(degS, rowtmp, bsum, NN);
    scanB<<<1, 256, 0, stream>>>(bsum, NBS);
    scanC<<<(NN + 256) / 256, 256, 0, stream>>>(rowtmp, bsum, rowptrS, NN, NE);
    scanA<<<NBS, 256, 0, stream>>>(degT, rowtmp, bsum, NN);
    scanB<<<1, 256, 0, stream>>>(bsum, NBS);
    scanC<<<(NN + 256) / 256, 256, 0, stream>>>(rowtmp, bsum, rowptrT, NN, NE);
    cpy2<<<(NN + 255) / 256, 256, 0, stream>>>(rowptrS, rowptrT, degS, degT, NN);
    fill2<<<2 * NBH, 256, 0, stream>>>(ei, tei, degS, degT, csrsS, csrsT);

    prep4<<<1, 256, 0, stream>>>(sa0, sa1, ta0, ta1, sum_a);

    auto run_layer = [&](const float* hin, int K, const float* W, int ai,
                         const float* g, const float* b,
                         const int* rowptr, const int* csrs,
                         float* accb, float* hout) {
        if (K == 8)
            gemm_k<8><<<(NN + 63) / 64, 256, 0, stream>>>(hin, W, buf_Wh, NN);
        else
            gemm_k<64><<<(NN + 63) / 64, 256, 0, stream>>>(hin, W, buf_Wh, NN);
        edge_agg<<<NBE, 256, 0, stream>>>(buf_Wh, rowptr, csrs, sum_a + ai,
                                          accb, mloc, bmax, bsumz, NN);
        combine_k<<<1, 256, 0, stream>>>(bmax, bsumz, mz, NBE);
        norm_ln<<<(NN + 3) / 4, 256, 0, stream>>>(accb, mloc, mz, g, b, hout, NN);
    };

    // spatial stack
    run_layer(x,     8,  sW0, 0, sg0, sb0, rowptrS, csrsS, buf_h, buf_h);
    run_layer(buf_h, 64, sW1, 1, sg1, sb1, rowptrS, csrsS, buf_h, buf_sp);
    // temporal stack
    run_layer(x,     8,  tW0, 2, tg0, tb0, rowptrT, csrsT, buf_h, buf_h);
    run_layer(buf_h, 64, tW1, 3, tg1, tb1, rowptrT, csrsT, buf_h, buf_h);

    final_kernel<<<(NN + 7) / 8, 256, 0, stream>>>(buf_sp, buf_h, cW1, cb1, cW2, cb2, out, NN);
}

// Round 6
// 548.034 us; speedup vs baseline: 71.9405x; 1.6430x over previous
//
#include <hip/hip_runtime.h>
#include <math.h>

#define NN 100000
#define NE 1600000
#define HID 64
#define NBE 2048                 // grid for edge_agg
#define EPB 2048                 // edges per bucket-build block
#define NBLK 782                 // ceil(NE/EPB)
#define NBUCK 98                 // ceil(NN/1024), bucket = dst>>10
#define MATN (2 * NBUCK * NBLK)  // count-matrix entries (both lists)

// online-softmax merge: (m,z) <- (m,z) (+) (m2,z2); nan-safe for -inf states
__device__ __forceinline__ void smerge(float& m, float& z, float m2, float z2) {
    if (m2 > m) { z = z * __expf(m - m2) + z2; m = m2; }
    else if (m2 > -INFINITY) { z += z2 * __expf(m2 - m); }
}

// ---- all four sum(a) scalars in one launch ----
__global__ void prep4(const float* __restrict__ a0, const float* __restrict__ a1,
                      const float* __restrict__ a2, const float* __restrict__ a3,
                      float* __restrict__ sum_a) {
    int w = threadIdx.x >> 6, lane = threadIdx.x & 63;
    const float* a = (w == 0) ? a0 : (w == 1) ? a1 : (w == 2) ? a2 : a3;
    float v = a[lane] + a[lane + 64];
    #pragma unroll
    for (int o = 32; o >= 1; o >>= 1) v += __shfl_xor(v, o);
    if (lane == 0) sum_a[w] = v;
}

// ================= CSR build: two-level bucket partition =================
// A1: per-block LDS histogram over 98 dst-buckets -> cnt[side][bucket][block]
__global__ void bucket_hist(const int* __restrict__ eiS, const int* __restrict__ eiT,
                            int* __restrict__ cnt) {
    __shared__ int hist[NBUCK];
    int t = threadIdx.x;
    int side = blockIdx.x >= NBLK;
    int blk = blockIdx.x - side * NBLK;
    const int* dst = (side ? eiT : eiS) + NE;
    if (t < NBUCK) hist[t] = 0;
    __syncthreads();
    int base = blk * EPB;
    #pragma unroll
    for (int k = 0; k < EPB / 256; k++) {
        int e = base + k * 256 + t;
        if (e < NE) atomicAdd(&hist[dst[e] >> 10], 1);
    }
    __syncthreads();
    if (t < NBUCK) cnt[side * (NBUCK * NBLK) + t * NBLK + blk] = hist[t];
}

// generic scan kernels (1024 elems/block, 256 thr x 4)
__global__ void scanA(const int* __restrict__ deg, int* __restrict__ rowtmp,
                      int* __restrict__ bsum, int n) {
    __shared__ int sh[256];
    int t = threadIdx.x;
    int base = blockIdx.x * 1024 + t * 4;
    int a0 = (base + 0 < n) ? deg[base + 0] : 0;
    int a1 = (base + 1 < n) ? deg[base + 1] : 0;
    int a2 = (base + 2 < n) ? deg[base + 2] : 0;
    int a3 = (base + 3 < n) ? deg[base + 3] : 0;
    int s = a0 + a1 + a2 + a3;
    sh[t] = s;
    __syncthreads();
    for (int off = 1; off < 256; off <<= 1) {
        int x = (t >= off) ? sh[t - off] : 0;
        __syncthreads();
        sh[t] += x;
        __syncthreads();
    }
    int excl = sh[t] - s;
    if (t == 255) bsum[blockIdx.x] = sh[255];
    if (base + 0 < n) rowtmp[base + 0] = excl;
    if (base + 1 < n) rowtmp[base + 1] = excl + a0;
    if (base + 2 < n) rowtmp[base + 2] = excl + a0 + a1;
    if (base + 3 < n) rowtmp[base + 3] = excl + a0 + a1 + a2;
}

__global__ void scanB(int* __restrict__ bsum, int nb) {
    __shared__ int sh[256];
    int t = threadIdx.x;
    int v = (t < nb) ? bsum[t] : 0;
    sh[t] = v;
    __syncthreads();
    for (int off = 1; off < 256; off <<= 1) {
        int x = (t >= off) ? sh[t - off] : 0;
        __syncthreads();
        sh[t] += x;
        __syncthreads();
    }
    if (t < nb) bsum[t] = sh[t] - v; // exclusive
}

__global__ void scanC(const int* __restrict__ rowtmp, const int* __restrict__ bsum,
                      int* __restrict__ outp, int n, int total) {
    int i = blockIdx.x * 256 + threadIdx.x;
    if (i < n) outp[i] = rowtmp[i] + bsum[i >> 10];
    if (i == n) outp[n] = total;
}

// A3: scatter (src,dst) pairs into bucket-partitioned part[] (dense-ish writes)
__global__ void bucket_scatter(const int* __restrict__ eiS, const int* __restrict__ eiT,
                               const int* __restrict__ off, int2* __restrict__ part) {
    __shared__ int cur[NBUCK];
    int t = threadIdx.x;
    int side = blockIdx.x >= NBLK;
    int blk = blockIdx.x - side * NBLK;
    const int* ei = side ? eiT : eiS;
    if (t < NBUCK) cur[t] = off[side * (NBUCK * NBLK) + t * NBLK + blk];
    __syncthreads();
    int base = blk * EPB;
    #pragma unroll
    for (int k = 0; k < EPB / 256; k++) {
        int e = base + k * 256 + t;
        if (e < NE) {
            int s = ei[e], d = ei[NE + e];
            int p = atomicAdd(&cur[d >> 10], 1);
            part[p] = make_int2(s, d);
        }
    }
}

// B: one block per (side,bucket): LDS hist + scan -> rowptr + csr fill
__global__ void bucket_csr(const int2* __restrict__ part, const int* __restrict__ off,
                           int* __restrict__ rowptrS, int* __restrict__ rowptrT,
                           int* __restrict__ csrsS, int* __restrict__ csrsT) {
    __shared__ int hist[1024];
    __shared__ int sh[1024];
    int t = threadIdx.x;           // 1024 threads
    int g = blockIdx.x;            // 0..2*NBUCK-1
    int side = g >= NBUCK;
    int bin = g - side * NBUCK;
    int start = off[g * NBLK];
    int end = off[(g + 1) * NBLK];     // off[MATN] = 2*NE sentinel
    hist[t] = 0;
    __syncthreads();
    for (int i = start + t; i < end; i += 1024)
        atomicAdd(&hist[part[i].y & 1023], 1);
    __syncthreads();
    int own = hist[t];
    sh[t] = own;
    __syncthreads();
    for (int o = 1; o < 1024; o <<= 1) {
        int x = (t >= o) ? sh[t - o] : 0;
        __syncthreads();
        sh[t] += x;
        __syncthreads();
    }
    int excl = sh[t] - own;
    int node = bin * 1024 + t;
    int* rowptr = side ? rowptrT : rowptrS;
    if (node < NN) rowptr[node] = (start - side * NE) + excl;
    if (t == 0 && bin == NBUCK - 1) rowptr[NN] = NE;
    __syncthreads();
    hist[t] = start + excl;            // reuse as global cursor (part-space)
    __syncthreads();
    int* csr = side ? csrsT : csrsS;
    int sub = side * NE;
    for (int i = start + t; i < end; i += 1024) {
        int2 e = part[i];
        int p = atomicAdd(&hist[e.y & 1023], 1);
        csr[p - sub] = e.x;
    }
}

// ---- GEMM: Wh[n][64] = h[n][K] @ W[K][64], float4 loads ----
template <int K>
__global__ void gemm_k(const float* __restrict__ h, const float* __restrict__ W,
                       float* __restrict__ Wh, int n) {
    __shared__ float Wl[K][HID];
    int t = threadIdx.x;
    for (int i = t; i < K * HID / 4; i += 256)
        ((float4*)Wl)[i] = ((const float4*)W)[i];
    __syncthreads();
    int node = blockIdx.x * 64 + (t >> 2);
    int c0 = (t & 3) * 16;
    if (node >= n) return;
    float acc[16];
    #pragma unroll
    for (int j = 0; j < 16; j++) acc[j] = 0.f;
    const float* hr = h + (size_t)node * K;
    #pragma unroll
    for (int k4 = 0; k4 < K / 4; k4++) {
        float4 hv = *(const float4*)(hr + k4 * 4);
        #pragma unroll
        for (int j = 0; j < 16; j++)
            acc[j] += hv.x * Wl[k4*4+0][c0+j] + hv.y * Wl[k4*4+1][c0+j]
                    + hv.z * Wl[k4*4+2][c0+j] + hv.w * Wl[k4*4+3][c0+j];
    }
    float* o = Wh + (size_t)node * HID + c0;
    #pragma unroll
    for (int j = 0; j < 16; j += 4)
        *(float4*)(o + j) = make_float4(acc[j], acc[j+1], acc[j+2], acc[j+3]);
}

// ---- single edge pass: online-softmax aggregate per node ----
// lane layout: 4 groups of 16 lanes; group g handles edge i+g, lane holds 4 dims.
__global__ void edge_agg(const float* __restrict__ Wh, const int* __restrict__ rowptr,
                         const int* __restrict__ csrs, const float* __restrict__ sum_a_p,
                         float* __restrict__ acc, float* __restrict__ mloc,
                         float* __restrict__ bmax, float* __restrict__ bsumz, int n) {
    int t = threadIdx.x;
    int w = t >> 6, lane = t & 63;
    int g = lane >> 4, l16 = lane & 15;
    float sa = *sum_a_p;
    float M = -INFINITY, Z = 0.f;                 // per-wave running block aggregate
    for (int node = blockIdx.x * 4 + w; node < n; node += NBE * 4) {
        float4 q4 = *(const float4*)(Wh + (size_t)node * HID + l16 * 4);
        int beg = rowptr[node], end = rowptr[node + 1];
        float m = -INFINITY, z = 0.f;
        float4 a4 = make_float4(0.f, 0.f, 0.f, 0.f);
        for (int i = beg; i < end; i += 4) {
            int idx = i + g;
            bool act = idx < end;
            int s = csrs[act ? idx : beg];
            float4 v4 = *(const float4*)(Wh + (size_t)s * HID + l16 * 4);
            float x = q4.x*v4.x + q4.y*v4.y + q4.z*v4.z + q4.w*v4.w;
            x += __shfl_xor(x, 1); x += __shfl_xor(x, 2);
            x += __shfl_xor(x, 4); x += __shfl_xor(x, 8);
            float e = x * sa;
            e = e > 0.f ? e : 0.2f * e;           // leaky_relu 0.2
            if (act) {
                if (e > m) {
                    float f = __expf(m - e);      // m=-inf -> 0, no nan
                    z *= f; a4.x *= f; a4.y *= f; a4.z *= f; a4.w *= f;
                    m = e;
                }
                float wgt = __expf(e - m);
                z += wgt;
                a4.x += wgt * v4.x; a4.y += wgt * v4.y;
                a4.z += wgt * v4.z; a4.w += wgt * v4.w;
            }
        }
        // merge the 4 groups' (m, z, acc4) via butterfly xor 16, 32
        #pragma unroll
        for (int o = 16; o <= 32; o <<= 1) {
            float mo = __shfl_xor(m, o), zo = __shfl_xor(z, o);
            float ax = __shfl_xor(a4.x, o), ay = __shfl_xor(a4.y, o);
            float az = __shfl_xor(a4.z, o), aw = __shfl_xor(a4.w, o);
            float mn = fmaxf(m, mo);
            float fs = (m  > -INFINITY) ? __expf(m  - mn) : 0.f;
            float fo = (mo > -INFINITY) ? __expf(mo - mn) : 0.f;
            z = z * fs + zo * fo;
            a4.x = a4.x*fs + ax*fo; a4.y = a4.y*fs + ay*fo;
            a4.z = a4.z*fs + az*fo; a4.w = a4.w*fs + aw*fo;
            m = mn;
        }
        if (g == 0) {
            *(float4*)(acc + (size_t)node * HID + l16 * 4) = a4;
            if (l16 == 0) mloc[node] = m;
        }
        smerge(M, Z, m, z);
    }
    __shared__ float shm[4], shz[4];
    if (lane == 0) { shm[w] = M; shz[w] = Z; }
    __syncthreads();
    if (t == 0) {
        float Mb = shm[0], Zb = shz[0];
        #pragma unroll
        for (int k = 1; k < 4; k++) smerge(Mb, Zb, shm[k], shz[k]);
        bmax[blockIdx.x] = Mb; bsumz[blockIdx.x] = Zb;
    }
}

// ---- combine 2048 block aggregates -> global m, 1/Z ----
__global__ void combine_k(const float* __restrict__ bmax, const float* __restrict__ bsumz,
                          float* __restrict__ mz, int nb) {
    int t = threadIdx.x; // 256
    float m = -INFINITY;
    for (int i = t; i < nb; i += 256) m = fmaxf(m, bmax[i]);
    #pragma unroll
    for (int o = 32; o >= 1; o >>= 1) m = fmaxf(m, __shfl_xor(m, o));
    __shared__ float sm[4];
    if ((t & 63) == 0) sm[t >> 6] = m;
    __syncthreads();
    m = fmaxf(fmaxf(sm[0], sm[1]), fmaxf(sm[2], sm[3]));
    double z = 0.0;
    for (int i = t; i < nb; i += 256) {
        float bm = bmax[i];
        if (bm > -INFINITY) z += (double)bsumz[i] * exp((double)bm - (double)m);
    }
    #pragma unroll
    for (int o = 32; o >= 1; o >>= 1) z += __shfl_xor(z, o);
    __shared__ double sz[4];
    if ((t & 63) == 0) sz[t >> 6] = z;
    __syncthreads();
    if (t == 0) { mz[0] = m; mz[1] = (float)(1.0 / (sz[0] + sz[1] + sz[2] + sz[3])); }
}

// ---- streaming normalize + elu + LayerNorm (safe in-place: acc may == out) ----
__global__ void norm_ln(const float* __restrict__ acc, const float* __restrict__ mloc,
                        const float* __restrict__ mz, const float* __restrict__ g,
                        const float* __restrict__ b, float* __restrict__ out, int n) {
    int node = blockIdx.x * 4 + (threadIdx.x >> 6);
    int lane = threadIdx.x & 63;
    if (node >= n) return;
    float scale = __expf(mloc[node] - mz[0]) * mz[1];   // mloc=-inf -> 0
    float v = acc[(size_t)node * HID + lane] * scale;
    v = v > 0.f ? v : expm1f(v);         // elu
    float s = v, s2 = v * v;
    #pragma unroll
    for (int o = 32; o >= 1; o >>= 1) {
        s += __shfl_xor(s, o);
        s2 += __shfl_xor(s2, o);
    }
    float mean = s * (1.f / 64.f);
    float var = s2 * (1.f / 64.f) - mean * mean;
    out[(size_t)node * HID + lane] = g[lane] * (v - mean) * rsqrtf(var + 1e-5f) + b[lane];
}

// ---- final: out = sigmoid(relu((sp+tp)@cW1+cb1)@cW2+cb2) ----
__global__ void final_kernel(const float* __restrict__ sp, const float* __restrict__ tp,
                             const float* __restrict__ cW1, const float* __restrict__ cb1,
                             const float* __restrict__ cW2, const float* __restrict__ cb2,
                             float* __restrict__ out, int n) {
    __shared__ float W1[64 * 32];
    __shared__ float W2[32];
    __shared__ float B1[32];
    __shared__ float hsh[8][64];
    int t = threadIdx.x;
    for (int i = t; i < 2048; i += 256) W1[i] = cW1[i];
    if (t < 32) { W2[t] = cW2[t]; B1[t] = cb1[t]; }
    __syncthreads();
    int ln = t >> 5;
    int j = t & 31;
    int node = blockIdx.x * 8 + ln;
    if (node < n) {
        hsh[ln][j]      = sp[(size_t)node * 64 + j]      + tp[(size_t)node * 64 + j];
        hsh[ln][j + 32] = sp[(size_t)node * 64 + j + 32] + tp[(size_t)node * 64 + j + 32];
    }
    __syncthreads();
    if (node >= n) return;
    float a = B1[j];
    #pragma unroll
    for (int k = 0; k < 64; k++) a += hsh[ln][k] * W1[k * 32 + j];
    a = fmaxf(a, 0.f);
    float p = a * W2[j];
    #pragma unroll
    for (int o = 16; o >= 1; o >>= 1) p += __shfl_xor(p, o, 32);
    if (j == 0) out[node] = 1.f / (1.f + expf(-(p + cb2[0])));
}

extern "C" void kernel_launch(void* const* d_in, const int* in_sizes, int n_in,
                              void* d_out, int out_size, void* d_ws, size_t ws_size,
                              hipStream_t stream) {
    const float* x   = (const float*)d_in[0];
    const int*   ei  = (const int*)d_in[1];
    const int*   tei = (const int*)d_in[3];
    const float* sW0 = (const float*)d_in[4],  *sa0 = (const float*)d_in[5];
    const float* sg0 = (const float*)d_in[6],  *sb0 = (const float*)d_in[7];
    const float* sW1 = (const float*)d_in[8],  *sa1 = (const float*)d_in[9];
    const float* sg1 = (const float*)d_in[10], *sb1 = (const float*)d_in[11];
    const float* tW0 = (const float*)d_in[12], *ta0 = (const float*)d_in[13];
    const float* tg0 = (const float*)d_in[14], *tb0 = (const float*)d_in[15];
    const float* tW1 = (const float*)d_in[16], *ta1 = (const float*)d_in[17];
    const float* tg1 = (const float*)d_in[18], *tb1 = (const float*)d_in[19];
    const float* cW1 = (const float*)d_in[20], *cb1 = (const float*)d_in[21];
    const float* cW2 = (const float*)d_in[22], *cb2 = (const float*)d_in[23];
    float* out = (float*)d_out;

    float* ws = (float*)d_ws;
    size_t o = 0;
    float* buf_h  = ws + o; o += (size_t)NN * HID;   // h / acc (aliased)
    float* buf_Wh = ws + o; o += (size_t)NN * HID;
    float* buf_sp = ws + o; o += (size_t)NN * HID;
    float* mloc   = ws + o; o += NN;
    float* bmax   = ws + o; o += NBE;
    float* bsumz  = ws + o; o += NBE;
    float* sum_a  = ws + o; o += 4;
    float* mz     = ws + o; o += 4;
    int* ip = (int*)(ws + o);
    int* rowptrS = ip; ip += NN + 1;
    int* rowptrT = ip; ip += NN + 1;
    int* csrsS   = ip; ip += NE;
    int* csrsT   = ip; ip += NE;

    // CSR-build scratch aliases buf_h/buf_Wh (only live before the layers)
    int2* part   = (int2*)buf_h;               // 3.2M pairs = 25.6 MB (== buf_h)
    int*  cnt    = (int*)buf_Wh;               // MATN+1
    int*  offm   = cnt + (MATN + 1);           // MATN+1
    int*  rowtmp = offm + (MATN + 1);          // MATN
    int*  bsum   = rowtmp + MATN;              // scan block sums

    const int NSB = (MATN + 1023) / 1024;      // 150 scanA blocks

    // ---- CSR build (both edge lists, bucket partition) ----
    bucket_hist<<<2 * NBLK, 256, 0, stream>>>(ei, tei, cnt);
    scanA<<<NSB, 256, 0, stream>>>(cnt, rowtmp, bsum, MATN);
    scanB<<<1, 256, 0, stream>>>(bsum, NSB);
    scanC<<<(MATN + 256) / 256, 256, 0, stream>>>(rowtmp, bsum, offm, MATN, 2 * NE);
    bucket_scatter<<<2 * NBLK, 256, 0, stream>>>(ei, tei, offm, part);
    bucket_csr<<<2 * NBUCK, 1024, 0, stream>>>(part, offm, rowptrS, rowptrT, csrsS, csrsT);

    prep4<<<1, 256, 0, stream>>>(sa0, sa1, ta0, ta1, sum_a);

    auto run_layer = [&](const float* hin, int K, const float* W, int ai,
                         const float* g, const float* b,
                         const int* rowptr, const int* csrs,
                         float* accb, float* hout) {
        if (K == 8)
            gemm_k<8><<<(NN + 63) / 64, 256, 0, stream>>>(hin, W, buf_Wh, NN);
        else
            gemm_k<64><<<(NN + 63) / 64, 256, 0, stream>>>(hin, W, buf_Wh, NN);
        edge_agg<<<NBE, 256, 0, stream>>>(buf_Wh, rowptr, csrs, sum_a + ai,
                                          accb, mloc, bmax, bsumz, NN);
        combine_k<<<1, 256, 0, stream>>>(bmax, bsumz, mz, NBE);
        norm_ln<<<(NN + 3) / 4, 256, 0, stream>>>(accb, mloc, mz, g, b, hout, NN);
    };

    // spatial stack
    run_layer(x,     8,  sW0, 0, sg0, sb0, rowptrS, csrsS, buf_h, buf_h);
    run_layer(buf_h, 64, sW1, 1, sg1, sb1, rowptrS, csrsS, buf_h, buf_sp);
    // temporal stack
    run_layer(x,     8,  tW0, 2, tg0, tb0, rowptrT, csrsT, buf_h, buf_h);
    run_layer(buf_h, 64, tW1, 3, tg1, tb1, rowptrT, csrsT, buf_h, buf_h);

    final_kernel<<<(NN + 7) / 8, 256, 0, stream>>>(buf_sp, buf_h, cW1, cb1, cW2, cb2, out, NN);
}

// Round 7
// 492.061 us; speedup vs baseline: 80.1238x; 1.1138x over previous
//
#include <hip/hip_runtime.h>
#include <math.h>

#define NN 100000
#define NE 1600000
#define HID 64
#define NBE 2048                 // edge_agg blocks per side
#define NBG 2048                 // normgemm blocks per side
#define NBF 2048                 // normfinal blocks
#define EPB 2048                 // edges per bucket-build block
#define NBLK 782                 // ceil(NE/EPB)
#define NBUCK 98                 // ceil(NN/1024), bucket = dst>>10
#define MATN (2 * NBUCK * NBLK)  // count-matrix entries (both lists)
#define BIGNEG -1.0e30f

// ---- all four sum(a) scalars in one launch ----
__global__ void prep4(const float* __restrict__ a0, const float* __restrict__ a1,
                      const float* __restrict__ a2, const float* __restrict__ a3,
                      float* __restrict__ sum_a) {
    int w = threadIdx.x >> 6, lane = threadIdx.x & 63;
    const float* a = (w == 0) ? a0 : (w == 1) ? a1 : (w == 2) ? a2 : a3;
    float v = a[lane] + a[lane + 64];
    #pragma unroll
    for (int o = 32; o >= 1; o >>= 1) v += __shfl_xor(v, o);
    if (lane == 0) sum_a[w] = v;
}

// ================= CSR build: two-level bucket partition =================
__global__ void bucket_hist(const int* __restrict__ eiS, const int* __restrict__ eiT,
                            int* __restrict__ cnt) {
    __shared__ int hist[NBUCK];
    int t = threadIdx.x;
    int side = blockIdx.x >= NBLK;
    int blk = blockIdx.x - side * NBLK;
    const int* dst = (side ? eiT : eiS) + NE;
    if (t < NBUCK) hist[t] = 0;
    __syncthreads();
    int base = blk * EPB;
    #pragma unroll
    for (int k = 0; k < EPB / 256; k++) {
        int e = base + k * 256 + t;
        if (e < NE) atomicAdd(&hist[dst[e] >> 10], 1);
    }
    __syncthreads();
    if (t < NBUCK) cnt[side * (NBUCK * NBLK) + t * NBLK + blk] = hist[t];
}

__global__ void scanA(const int* __restrict__ deg, int* __restrict__ rowtmp,
                      int* __restrict__ bsum, int n) {
    __shared__ int sh[256];
    int t = threadIdx.x;
    int base = blockIdx.x * 1024 + t * 4;
    int a0 = (base + 0 < n) ? deg[base + 0] : 0;
    int a1 = (base + 1 < n) ? deg[base + 1] : 0;
    int a2 = (base + 2 < n) ? deg[base + 2] : 0;
    int a3 = (base + 3 < n) ? deg[base + 3] : 0;
    int s = a0 + a1 + a2 + a3;
    sh[t] = s;
    __syncthreads();
    for (int off = 1; off < 256; off <<= 1) {
        int x = (t >= off) ? sh[t - off] : 0;
        __syncthreads();
        sh[t] += x;
        __syncthreads();
    }
    int excl = sh[t] - s;
    if (t == 255) bsum[blockIdx.x] = sh[255];
    if (base + 0 < n) rowtmp[base + 0] = excl;
    if (base + 1 < n) rowtmp[base + 1] = excl + a0;
    if (base + 2 < n) rowtmp[base + 2] = excl + a0 + a1;
    if (base + 3 < n) rowtmp[base + 3] = excl + a0 + a1 + a2;
}

__global__ void scanB(int* __restrict__ bsum, int nb) {
    __shared__ int sh[256];
    int t = threadIdx.x;
    int v = (t < nb) ? bsum[t] : 0;
    sh[t] = v;
    __syncthreads();
    for (int off = 1; off < 256; off <<= 1) {
        int x = (t >= off) ? sh[t - off] : 0;
        __syncthreads();
        sh[t] += x;
        __syncthreads();
    }
    if (t < nb) bsum[t] = sh[t] - v; // exclusive
}

__global__ void scanC(const int* __restrict__ rowtmp, const int* __restrict__ bsum,
                      int* __restrict__ outp, int n, int total) {
    int i = blockIdx.x * 256 + threadIdx.x;
    if (i < n) outp[i] = rowtmp[i] + bsum[i >> 10];
    if (i == n) outp[n] = total;
}

__global__ void bucket_scatter(const int* __restrict__ eiS, const int* __restrict__ eiT,
                               const int* __restrict__ off, int2* __restrict__ part) {
    __shared__ int cur[NBUCK];
    int t = threadIdx.x;
    int side = blockIdx.x >= NBLK;
    int blk = blockIdx.x - side * NBLK;
    const int* ei = side ? eiT : eiS;
    if (t < NBUCK) cur[t] = off[side * (NBUCK * NBLK) + t * NBLK + blk];
    __syncthreads();
    int base = blk * EPB;
    #pragma unroll
    for (int k = 0; k < EPB / 256; k++) {
        int e = base + k * 256 + t;
        if (e < NE) {
            int s = ei[e], d = ei[NE + e];
            int p = atomicAdd(&cur[d >> 10], 1);
            part[p] = make_int2(s, d);
        }
    }
}

__global__ void bucket_csr(const int2* __restrict__ part, const int* __restrict__ off,
                           int* __restrict__ rowptrS, int* __restrict__ rowptrT,
                           int* __restrict__ csrsS, int* __restrict__ csrsT) {
    __shared__ int hist[1024];
    __shared__ int sh[1024];
    int t = threadIdx.x;           // 1024 threads
    int g = blockIdx.x;            // 0..2*NBUCK-1
    int side = g >= NBUCK;
    int bin = g - side * NBUCK;
    int start = off[g * NBLK];
    int end = off[(g + 1) * NBLK];
    hist[t] = 0;
    __syncthreads();
    for (int i = start + t; i < end; i += 1024)
        atomicAdd(&hist[part[i].y & 1023], 1);
    __syncthreads();
    int own = hist[t];
    sh[t] = own;
    __syncthreads();
    for (int o = 1; o < 1024; o <<= 1) {
        int x = (t >= o) ? sh[t - o] : 0;
        __syncthreads();
        sh[t] += x;
        __syncthreads();
    }
    int excl = sh[t] - own;
    int node = bin * 1024 + t;
    int* rowptr = side ? rowptrT : rowptrS;
    if (node < NN) rowptr[node] = (start - side * NE) + excl;
    if (t == 0 && bin == NBUCK - 1) rowptr[NN] = NE;
    __syncthreads();
    hist[t] = start + excl;
    __syncthreads();
    int* csr = side ? csrsT : csrsS;
    int sub = side * NE;
    for (int i = start + t; i < end; i += 1024) {
        int2 e = part[i];
        int p = atomicAdd(&hist[e.y & 1023], 1);
        csr[p - sub] = e.x;
    }
}

// ---- batched L0 GEMM (K=8): WhS = x@WS, WhT = x@WT ----
__global__ void gemm2_k8(const float* __restrict__ x, const float* __restrict__ WS,
                         const float* __restrict__ WT, float* __restrict__ WhS,
                         float* __restrict__ WhT, int n) {
    const int nbh = (NN + 63) / 64;
    int side = blockIdx.x >= nbh;
    int blk = blockIdx.x - side * nbh;
    const float* W = side ? WT : WS;
    float* Wh = side ? WhT : WhS;
    __shared__ float Wl[8][HID];
    int t = threadIdx.x;
    for (int i = t; i < 8 * HID / 4; i += 256)
        ((float4*)Wl)[i] = ((const float4*)W)[i];
    __syncthreads();
    int node = blk * 64 + (t >> 2);
    int c0 = (t & 3) * 16;
    if (node >= n) return;
    float acc[16];
    #pragma unroll
    for (int j = 0; j < 16; j++) acc[j] = 0.f;
    const float* hr = x + (size_t)node * 8;
    #pragma unroll
    for (int k4 = 0; k4 < 2; k4++) {
        float4 hv = *(const float4*)(hr + k4 * 4);
        #pragma unroll
        for (int j = 0; j < 16; j++)
            acc[j] += hv.x * Wl[k4*4+0][c0+j] + hv.y * Wl[k4*4+1][c0+j]
                    + hv.z * Wl[k4*4+2][c0+j] + hv.w * Wl[k4*4+3][c0+j];
    }
    float* o = Wh + (size_t)node * HID + c0;
    #pragma unroll
    for (int j = 0; j < 16; j += 4)
        *(float4*)(o + j) = make_float4(acc[j], acc[j+1], acc[j+2], acc[j+3]);
}

// ---- batched single-pass edge aggregation (both sides), 8-lane groups ----
// lane layout: 8 groups of 8 lanes; group g handles edge i+g; lane holds 8 dims.
__global__ void edge_agg2(const float* __restrict__ WhS, const float* __restrict__ WhT,
                          const int* __restrict__ rowptrS, const int* __restrict__ rowptrT,
                          const int* __restrict__ csrsS, const int* __restrict__ csrsT,
                          const float* __restrict__ sum_a, int aiS, int aiT,
                          float* __restrict__ accS, float* __restrict__ accT,
                          float* __restrict__ mlocS, float* __restrict__ mlocT,
                          float* __restrict__ bmax, float* __restrict__ bsumz, int n) {
    int side = blockIdx.x >= NBE;
    int blk = blockIdx.x - side * NBE;
    const float* Wh = side ? WhT : WhS;
    const int* rowptr = side ? rowptrT : rowptrS;
    const int* csrs = side ? csrsT : csrsS;
    float* acc = side ? accT : accS;
    float* mloc = side ? mlocT : mlocS;
    float sa = sum_a[side ? aiT : aiS];
    int t = threadIdx.x;
    int w = t >> 6, lane = t & 63;
    int g = lane >> 3, l8 = lane & 7;
    float M = BIGNEG, Z = 0.f;
    for (int node = blk * 4 + w; node < n; node += NBE * 4) {
        const float* qp = Wh + (size_t)node * HID + l8 * 8;
        float4 q0 = *(const float4*)qp, q1 = *(const float4*)(qp + 4);
        int beg = rowptr[node], end = rowptr[node + 1];
        float m = BIGNEG, z = 0.f;
        float4 a0 = make_float4(0,0,0,0), a1 = make_float4(0,0,0,0);
        for (int i = beg; i < end; i += 8) {
            int idx = i + g;
            bool act = idx < end;
            int s = csrs[act ? idx : beg];
            const float* vp = Wh + (size_t)s * HID + l8 * 8;
            float4 v0 = *(const float4*)vp, v1 = *(const float4*)(vp + 4);
            float x = q0.x*v0.x + q0.y*v0.y + q0.z*v0.z + q0.w*v0.w
                    + q1.x*v1.x + q1.y*v1.y + q1.z*v1.z + q1.w*v1.w;
            x += __shfl_xor(x, 1); x += __shfl_xor(x, 2); x += __shfl_xor(x, 4);
            float e = x * sa;
            e = e > 0.f ? e : 0.2f * e;           // leaky_relu 0.2
            e = act ? e : BIGNEG;
            float mn = fmaxf(m, e);
            float fs = __expf(m - mn);
            float wg = act ? __expf(e - mn) : 0.f;
            z = z * fs + wg;
            a0.x = a0.x*fs + wg*v0.x; a0.y = a0.y*fs + wg*v0.y;
            a0.z = a0.z*fs + wg*v0.z; a0.w = a0.w*fs + wg*v0.w;
            a1.x = a1.x*fs + wg*v1.x; a1.y = a1.y*fs + wg*v1.y;
            a1.z = a1.z*fs + wg*v1.z; a1.w = a1.w*fs + wg*v1.w;
            m = mn;
        }
        // merge 8 groups: butterfly xor 8,16,32 on (m,z,a8)
        #pragma unroll
        for (int o = 8; o <= 32; o <<= 1) {
            float mo = __shfl_xor(m, o), zo = __shfl_xor(z, o);
            float b0x = __shfl_xor(a0.x, o), b0y = __shfl_xor(a0.y, o);
            float b0z = __shfl_xor(a0.z, o), b0w = __shfl_xor(a0.w, o);
            float b1x = __shfl_xor(a1.x, o), b1y = __shfl_xor(a1.y, o);
            float b1z = __shfl_xor(a1.z, o), b1w = __shfl_xor(a1.w, o);
            float mn = fmaxf(m, mo);
            float fs = __expf(m - mn), fo = __expf(mo - mn);
            z = z * fs + zo * fo;
            a0.x = a0.x*fs + b0x*fo; a0.y = a0.y*fs + b0y*fo;
            a0.z = a0.z*fs + b0z*fo; a0.w = a0.w*fs + b0w*fo;
            a1.x = a1.x*fs + b1x*fo; a1.y = a1.y*fs + b1y*fo;
            a1.z = a1.z*fs + b1z*fo; a1.w = a1.w*fs + b1w*fo;
            m = mn;
        }
        if (g == 0) {
            float* ap = acc + (size_t)node * HID + l8 * 8;
            *(float4*)ap = a0; *(float4*)(ap + 4) = a1;
            if (l8 == 0) mloc[node] = m;
        }
        // wave running aggregate
        float mn2 = fmaxf(M, m);
        Z = Z * __expf(M - mn2) + z * __expf(m - mn2);
        M = mn2;
    }
    __shared__ float shm[4], shz[4];
    if (lane == 0) { shm[w] = M; shz[w] = Z; }
    __syncthreads();
    if (t == 0) {
        float Mb = shm[0], Zb = shz[0];
        #pragma unroll
        for (int k = 1; k < 4; k++) {
            float mn = fmaxf(Mb, shm[k]);
            Zb = Zb * __expf(Mb - mn) + shz[k] * __expf(shm[k] - mn);
            Mb = mn;
        }
        bmax[blockIdx.x] = Mb; bsumz[blockIdx.x] = Zb;
    }
}

// in-block combine helper: global (m, invZ) for one side from block stats
__device__ __forceinline__ void combine_side(const float* __restrict__ bmax,
                                             const float* __restrict__ bsumz,
                                             int base, float* shred, float& gm, float& invZ) {
    int t = threadIdx.x;
    float lm = BIGNEG;
    for (int i = t; i < NBE; i += 256) lm = fmaxf(lm, bmax[base + i]);
    #pragma unroll
    for (int o = 32; o >= 1; o >>= 1) lm = fmaxf(lm, __shfl_xor(lm, o));
    if ((t & 63) == 0) shred[t >> 6] = lm;
    __syncthreads();
    float m = fmaxf(fmaxf(shred[0], shred[1]), fmaxf(shred[2], shred[3]));
    __syncthreads();
    float lz = 0.f;
    for (int i = t; i < NBE; i += 256) lz += bsumz[base + i] * __expf(bmax[base + i] - m);
    #pragma unroll
    for (int o = 32; o >= 1; o >>= 1) lz += __shfl_xor(lz, o);
    if ((t & 63) == 0) shred[t >> 6] = lz;
    __syncthreads();
    float Zt = (shred[0] + shred[1]) + (shred[2] + shred[3]);
    __syncthreads();
    gm = m; invZ = 1.f / Zt;
}

// ---- fused: combine + normalize + elu + LN(g0,b0) + GEMM(W1) -> Wh1, both sides ----
__global__ void normgemm2(const float* __restrict__ accS, const float* __restrict__ accT,
                          const float* __restrict__ mlocS, const float* __restrict__ mlocT,
                          const float* __restrict__ bmax, const float* __restrict__ bsumz,
                          const float* __restrict__ gS, const float* __restrict__ bS,
                          const float* __restrict__ gT, const float* __restrict__ bT,
                          const float* __restrict__ W1S, const float* __restrict__ W1T,
                          float* __restrict__ WhS, float* __restrict__ WhT, int n) {
    int side = blockIdx.x >= NBG;
    int blk = blockIdx.x - side * NBG;
    const float* acc = side ? accT : accS;
    const float* mloc = side ? mlocT : mlocS;
    const float* g = side ? gT : gS;
    const float* b = side ? bT : bS;
    const float* W1 = side ? W1T : W1S;
    float* Wh = side ? WhT : WhS;
    __shared__ float shred[4];
    float gm, invZ;
    combine_side(bmax, bsumz, side * NBE, shred, gm, invZ);
    __shared__ float Wl[64 * 64];
    int t = threadIdx.x;
    for (int i = t; i < 1024; i += 256)
        ((float4*)Wl)[i] = ((const float4*)W1)[i];
    __syncthreads();
    __shared__ float hrow[4][64];
    int w = t >> 6, lane = t & 63;
    float gl = g[lane], bl = b[lane];
    for (int node = blk * 4 + w; node < n; node += NBG * 4) {
        float scale = __expf(mloc[node] - gm) * invZ;
        float v = acc[(size_t)node * HID + lane] * scale;
        v = v > 0.f ? v : expm1f(v);         // elu
        float s = v, s2 = v * v;
        #pragma unroll
        for (int o = 32; o >= 1; o >>= 1) {
            s += __shfl_xor(s, o);
            s2 += __shfl_xor(s2, o);
        }
        float mean = s * (1.f / 64.f);
        float var = s2 * (1.f / 64.f) - mean * mean;
        float hn = gl * (v - mean) * rsqrtf(var + 1e-5f) + bl;
        hrow[w][lane] = hn;
        float o2 = 0.f;
        #pragma unroll
        for (int k = 0; k < 64; k++) o2 += hrow[w][k] * Wl[k * 64 + lane];
        Wh[(size_t)node * HID + lane] = o2;
    }
}

// ---- fused: combine(both sides) + normalize + elu + LN(g1,b1) + final MLP ----
__global__ void normfinal(const float* __restrict__ accS, const float* __restrict__ accT,
                          const float* __restrict__ mlocS, const float* __restrict__ mlocT,
                          const float* __restrict__ bmax, const float* __restrict__ bsumz,
                          const float* __restrict__ gS, const float* __restrict__ bS,
                          const float* __restrict__ gT, const float* __restrict__ bT,
                          const float* __restrict__ cW1, const float* __restrict__ cb1,
                          const float* __restrict__ cW2, const float* __restrict__ cb2,
                          float* __restrict__ out, int n) {
    __shared__ float shred[4];
    float gmS, invZS, gmT, invZT;
    combine_side(bmax, bsumz, 0, shred, gmS, invZS);
    combine_side(bmax, bsumz, NBE, shred, gmT, invZT);
    __shared__ float W1l[64 * 32];
    __shared__ float W2l[32], B1l[32];
    int t = threadIdx.x;
    for (int i = t; i < 512; i += 256)
        ((float4*)W1l)[i] = ((const float4*)cW1)[i];
    if (t < 32) { W2l[t] = cW2[t]; B1l[t] = cb1[t]; }
    __syncthreads();
    float c2 = cb2[0];
    __shared__ float hrow[4][64];
    int w = t >> 6, lane = t & 63;
    int j = lane & 31;
    float glS = gS[lane], blS = bS[lane], glT = gT[lane], blT = bT[lane];
    for (int node = blockIdx.x * 4 + w; node < n; node += NBF * 4) {
        // side S
        float vS = accS[(size_t)node * HID + lane] * (__expf(mlocS[node] - gmS) * invZS);
        vS = vS > 0.f ? vS : expm1f(vS);
        float sA = vS, sB = vS * vS;
        #pragma unroll
        for (int o = 32; o >= 1; o >>= 1) { sA += __shfl_xor(sA, o); sB += __shfl_xor(sB, o); }
        float meanS = sA * (1.f / 64.f);
        float varS = sB * (1.f / 64.f) - meanS * meanS;
        float hS = glS * (vS - meanS) * rsqrtf(varS + 1e-5f) + blS;
        // side T
        float vT = accT[(size_t)node * HID + lane] * (__expf(mlocT[node] - gmT) * invZT);
        vT = vT > 0.f ? vT : expm1f(vT);
        sA = vT; sB = vT * vT;
        #pragma unroll
        for (int o = 32; o >= 1; o >>= 1) { sA += __shfl_xor(sA, o); sB += __shfl_xor(sB, o); }
        float meanT = sA * (1.f / 64.f);
        float varT = sB * (1.f / 64.f) - meanT * meanT;
        float hT = glT * (vT - meanT) * rsqrtf(varT + 1e-5f) + blT;
        hrow[w][lane] = hS + hT;
        // MLP (lanes 0-31 and 32-63 compute the same j redundantly)
        float a = B1l[j];
        #pragma unroll
        for (int k = 0; k < 64; k++) a += hrow[w][k] * W1l[k * 32 + j];
        a = fmaxf(a, 0.f);
        float p = a * W2l[j];
        #pragma unroll
        for (int o = 16; o >= 1; o >>= 1) p += __shfl_xor(p, o, 32);
        if (lane == 0) out[node] = 1.f / (1.f + expf(-(p + c2)));
    }
}

extern "C" void kernel_launch(void* const* d_in, const int* in_sizes, int n_in,
                              void* d_out, int out_size, void* d_ws, size_t ws_size,
                              hipStream_t stream) {
    const float* x   = (const float*)d_in[0];
    const int*   ei  = (const int*)d_in[1];
    const int*   tei = (const int*)d_in[3];
    const float* sW0 = (const float*)d_in[4],  *sa0 = (const float*)d_in[5];
    const float* sg0 = (const float*)d_in[6],  *sb0 = (const float*)d_in[7];
    const float* sW1 = (const float*)d_in[8],  *sa1 = (const float*)d_in[9];
    const float* sg1 = (const float*)d_in[10], *sb1 = (const float*)d_in[11];
    const float* tW0 = (const float*)d_in[12], *ta0 = (const float*)d_in[13];
    const float* tg0 = (const float*)d_in[14], *tb0 = (const float*)d_in[15];
    const float* tW1 = (const float*)d_in[16], *ta1 = (const float*)d_in[17];
    const float* tg1 = (const float*)d_in[18], *tb1 = (const float*)d_in[19];
    const float* cW1 = (const float*)d_in[20], *cb1 = (const float*)d_in[21];
    const float* cW2 = (const float*)d_in[22], *cb2 = (const float*)d_in[23];
    float* out = (float*)d_out;

    float* ws = (float*)d_ws;
    size_t o = 0;
    float* hS  = ws + o; o += (size_t)NN * HID;   // acc S (aliased across layers)
    float* hT  = ws + o; o += (size_t)NN * HID;   // acc T
    float* WhS = ws + o; o += (size_t)NN * HID;
    float* WhT = ws + o; o += (size_t)NN * HID;
    float* mlocS = ws + o; o += NN;
    float* mlocT = ws + o; o += NN;
    float* bmax  = ws + o; o += 2 * NBE;
    float* bsumz = ws + o; o += 2 * NBE;
    float* sum_a = ws + o; o += 4;
    int* ip = (int*)(ws + o);
    int* rowptrS = ip; ip += NN + 1;
    int* rowptrT = ip; ip += NN + 1;
    int* csrsS   = ip; ip += NE;
    int* csrsT   = ip; ip += NE;

    // CSR-build scratch aliases WhS/WhT (only live before the layers)
    int2* part   = (int2*)WhS;                 // 3.2M pairs = 25.6 MB
    int*  cnt    = (int*)WhT;                  // MATN+1
    int*  offm   = cnt + (MATN + 1);
    int*  rowtmp = offm + (MATN + 1);
    int*  bsum   = rowtmp + MATN;

    const int NSB = (MATN + 1023) / 1024;

    // ---- CSR build (both edge lists, bucket partition) ----
    bucket_hist<<<2 * NBLK, 256, 0, stream>>>(ei, tei, cnt);
    scanA<<<NSB, 256, 0, stream>>>(cnt, rowtmp, bsum, MATN);
    scanB<<<1, 256, 0, stream>>>(bsum, NSB);
    scanC<<<(MATN + 256) / 256, 256, 0, stream>>>(rowtmp, bsum, offm, MATN, 2 * NE);
    bucket_scatter<<<2 * NBLK, 256, 0, stream>>>(ei, tei, offm, part);
    bucket_csr<<<2 * NBUCK, 1024, 0, stream>>>(part, offm, rowptrS, rowptrT, csrsS, csrsT);

    prep4<<<1, 256, 0, stream>>>(sa0, sa1, ta0, ta1, sum_a);

    const int nbh = (NN + 63) / 64;

    // ---- layer 0 (batched S+T) ----
    gemm2_k8<<<2 * nbh, 256, 0, stream>>>(x, sW0, tW0, WhS, WhT, NN);
    edge_agg2<<<2 * NBE, 256, 0, stream>>>(WhS, WhT, rowptrS, rowptrT, csrsS, csrsT,
                                           sum_a, 0, 2, hS, hT, mlocS, mlocT,
                                           bmax, bsumz, NN);
    // L0 norm + L1 GEMM fused
    normgemm2<<<2 * NBG, 256, 0, stream>>>(hS, hT, mlocS, mlocT, bmax, bsumz,
                                           sg0, sb0, tg0, tb0, sW1, tW1, WhS, WhT, NN);
    // ---- layer 1 (batched S+T) ----
    edge_agg2<<<2 * NBE, 256, 0, stream>>>(WhS, WhT, rowptrS, rowptrT, csrsS, csrsT,
                                           sum_a, 1, 3, hS, hT, mlocS, mlocT,
                                           bmax, bsumz, NN);
    // L1 norm + final MLP fused
    normfinal<<<NBF, 256, 0, stream>>>(hS, hT, mlocS, mlocT, bmax, bsumz,
                                       sg1, sb1, tg1, tb1, cW1, cb1, cW2, cb2, out, NN);
}

// Round 8
// 465.777 us; speedup vs baseline: 84.6453x; 1.0564x over previous
//
#include <hip/hip_runtime.h>
#include <math.h>

#define NN 100000
#define NE 1600000
#define HID 64
#define NBE 2048                 // edge_agg blocks per side
#define NBG 2048                 // normgemm blocks per side
#define NBF 2048                 // normfinal blocks
#define EPB 2048                 // edges per bucket-build block
#define NBLK 782                 // ceil(NE/EPB)
#define NBUCK 98                 // ceil(NN/1024), bucket = dst>>10
#define MATN (2 * NBUCK * NBLK)  // count-matrix entries (both lists)
#define ESHIFT 30.0f             // fixed exponent shift: w = exp(e - ESHIFT)

// ---- all four sum(a) scalars in one launch ----
__global__ void prep4(const float* __restrict__ a0, const float* __restrict__ a1,
                      const float* __restrict__ a2, const float* __restrict__ a3,
                      float* __restrict__ sum_a) {
    int w = threadIdx.x >> 6, lane = threadIdx.x & 63;
    const float* a = (w == 0) ? a0 : (w == 1) ? a1 : (w == 2) ? a2 : a3;
    float v = a[lane] + a[lane + 64];
    #pragma unroll
    for (int o = 32; o >= 1; o >>= 1) v += __shfl_xor(v, o);
    if (lane == 0) sum_a[w] = v;
}

// ================= CSR build: two-level bucket partition =================
__global__ void bucket_hist(const int* __restrict__ eiS, const int* __restrict__ eiT,
                            int* __restrict__ cnt) {
    __shared__ int hist[NBUCK];
    int t = threadIdx.x;
    int side = blockIdx.x >= NBLK;
    int blk = blockIdx.x - side * NBLK;
    const int* dst = (side ? eiT : eiS) + NE;
    if (t < NBUCK) hist[t] = 0;
    __syncthreads();
    int base = blk * EPB;
    #pragma unroll
    for (int k = 0; k < EPB / 256; k++) {
        int e = base + k * 256 + t;
        if (e < NE) atomicAdd(&hist[dst[e] >> 10], 1);
    }
    __syncthreads();
    if (t < NBUCK) cnt[side * (NBUCK * NBLK) + t * NBLK + blk] = hist[t];
}

__global__ void scanA(const int* __restrict__ deg, int* __restrict__ rowtmp,
                      int* __restrict__ bsum, int n) {
    __shared__ int sh[256];
    int t = threadIdx.x;
    int base = blockIdx.x * 1024 + t * 4;
    int a0 = (base + 0 < n) ? deg[base + 0] : 0;
    int a1 = (base + 1 < n) ? deg[base + 1] : 0;
    int a2 = (base + 2 < n) ? deg[base + 2] : 0;
    int a3 = (base + 3 < n) ? deg[base + 3] : 0;
    int s = a0 + a1 + a2 + a3;
    sh[t] = s;
    __syncthreads();
    for (int off = 1; off < 256; off <<= 1) {
        int x = (t >= off) ? sh[t - off] : 0;
        __syncthreads();
        sh[t] += x;
        __syncthreads();
    }
    int excl = sh[t] - s;
    if (t == 255) bsum[blockIdx.x] = sh[255];
    if (base + 0 < n) rowtmp[base + 0] = excl;
    if (base + 1 < n) rowtmp[base + 1] = excl + a0;
    if (base + 2 < n) rowtmp[base + 2] = excl + a0 + a1;
    if (base + 3 < n) rowtmp[base + 3] = excl + a0 + a1 + a2;
}

__global__ void scanB(int* __restrict__ bsum, int nb) {
    __shared__ int sh[256];
    int t = threadIdx.x;
    int v = (t < nb) ? bsum[t] : 0;
    sh[t] = v;
    __syncthreads();
    for (int off = 1; off < 256; off <<= 1) {
        int x = (t >= off) ? sh[t - off] : 0;
        __syncthreads();
        sh[t] += x;
        __syncthreads();
    }
    if (t < nb) bsum[t] = sh[t] - v; // exclusive
}

__global__ void scanC(const int* __restrict__ rowtmp, const int* __restrict__ bsum,
                      int* __restrict__ outp, int n, int total) {
    int i = blockIdx.x * 256 + threadIdx.x;
    if (i < n) outp[i] = rowtmp[i] + bsum[i >> 10];
    if (i == n) outp[n] = total;
}

__global__ void bucket_scatter(const int* __restrict__ eiS, const int* __restrict__ eiT,
                               const int* __restrict__ off, int2* __restrict__ part) {
    __shared__ int cur[NBUCK];
    int t = threadIdx.x;
    int side = blockIdx.x >= NBLK;
    int blk = blockIdx.x - side * NBLK;
    const int* ei = side ? eiT : eiS;
    if (t < NBUCK) cur[t] = off[side * (NBUCK * NBLK) + t * NBLK + blk];
    __syncthreads();
    int base = blk * EPB;
    #pragma unroll
    for (int k = 0; k < EPB / 256; k++) {
        int e = base + k * 256 + t;
        if (e < NE) {
            int s = ei[e], d = ei[NE + e];
            int p = atomicAdd(&cur[d >> 10], 1);
            part[p] = make_int2(s, d);
        }
    }
}

__global__ void bucket_csr(const int2* __restrict__ part, const int* __restrict__ off,
                           int* __restrict__ rowptrS, int* __restrict__ rowptrT,
                           int* __restrict__ csrsS, int* __restrict__ csrsT) {
    __shared__ int hist[1024];
    __shared__ int sh[1024];
    int t = threadIdx.x;           // 1024 threads
    int g = blockIdx.x;            // 0..2*NBUCK-1
    int side = g >= NBUCK;
    int bin = g - side * NBUCK;
    int start = off[g * NBLK];
    int end = off[(g + 1) * NBLK];
    hist[t] = 0;
    __syncthreads();
    for (int i = start + t; i < end; i += 1024)
        atomicAdd(&hist[part[i].y & 1023], 1);
    __syncthreads();
    int own = hist[t];
    sh[t] = own;
    __syncthreads();
    for (int o = 1; o < 1024; o <<= 1) {
        int x = (t >= o) ? sh[t - o] : 0;
        __syncthreads();
        sh[t] += x;
        __syncthreads();
    }
    int excl = sh[t] - own;
    int node = bin * 1024 + t;
    int* rowptr = side ? rowptrT : rowptrS;
    if (node < NN) rowptr[node] = (start - side * NE) + excl;
    if (t == 0 && bin == NBUCK - 1) rowptr[NN] = NE;
    __syncthreads();
    hist[t] = start + excl;
    __syncthreads();
    int* csr = side ? csrsT : csrsS;
    int sub = side * NE;
    for (int i = start + t; i < end; i += 1024) {
        int2 e = part[i];
        int p = atomicAdd(&hist[e.y & 1023], 1);
        csr[p - sub] = e.x;
    }
}

// ---- batched L0 GEMM (K=8): WhS = x@WS, WhT = x@WT ----
__global__ void gemm2_k8(const float* __restrict__ x, const float* __restrict__ WS,
                         const float* __restrict__ WT, float* __restrict__ WhS,
                         float* __restrict__ WhT, int n) {
    const int nbh = (NN + 63) / 64;
    int side = blockIdx.x >= nbh;
    int blk = blockIdx.x - side * nbh;
    const float* W = side ? WT : WS;
    float* Wh = side ? WhT : WhS;
    __shared__ float Wl[8][HID];
    int t = threadIdx.x;
    for (int i = t; i < 8 * HID / 4; i += 256)
        ((float4*)Wl)[i] = ((const float4*)W)[i];
    __syncthreads();
    int node = blk * 64 + (t >> 2);
    int c0 = (t & 3) * 16;
    if (node >= n) return;
    float acc[16];
    #pragma unroll
    for (int j = 0; j < 16; j++) acc[j] = 0.f;
    const float* hr = x + (size_t)node * 8;
    #pragma unroll
    for (int k4 = 0; k4 < 2; k4++) {
        float4 hv = *(const float4*)(hr + k4 * 4);
        #pragma unroll
        for (int j = 0; j < 16; j++)
            acc[j] += hv.x * Wl[k4*4+0][c0+j] + hv.y * Wl[k4*4+1][c0+j]
                    + hv.z * Wl[k4*4+2][c0+j] + hv.w * Wl[k4*4+3][c0+j];
    }
    float* o = Wh + (size_t)node * HID + c0;
    #pragma unroll
    for (int j = 0; j < 16; j += 4)
        *(float4*)(o + j) = make_float4(acc[j], acc[j+1], acc[j+2], acc[j+3]);
}

// ---- batched single-pass edge aggregation (both sides), fixed-shift exp ----
// lane layout: 8 groups of 8 lanes; group g handles edge i+g; lane holds 8 dims.
// acc[node] = sum_e exp(e - ESHIFT) * v ;  z = sum_e exp(e - ESHIFT)
__global__ void edge_agg2(const float* __restrict__ WhS, const float* __restrict__ WhT,
                          const int* __restrict__ rowptrS, const int* __restrict__ rowptrT,
                          const int* __restrict__ csrsS, const int* __restrict__ csrsT,
                          const float* __restrict__ sum_a, int aiS, int aiT,
                          float* __restrict__ accS, float* __restrict__ accT,
                          float* __restrict__ bsumz, int n) {
    int side = blockIdx.x >= NBE;
    int blk = blockIdx.x - side * NBE;
    const float* Wh = side ? WhT : WhS;
    const int* rowptr = side ? rowptrT : rowptrS;
    const int* csrs = side ? csrsT : csrsS;
    float* acc = side ? accT : accS;
    float sa = sum_a[side ? aiT : aiS];
    int t = threadIdx.x;
    int w = t >> 6, lane = t & 63;
    int g = lane >> 3, l8 = lane & 7;
    float Zw = 0.f;                               // wave-level z accumulator
    for (int node = blk * 4 + w; node < n; node += NBE * 4) {
        const float* qp = Wh + (size_t)node * HID + l8 * 8;
        float4 q0 = *(const float4*)qp, q1 = *(const float4*)(qp + 4);
        int beg = rowptr[node], end = rowptr[node + 1];
        float z = 0.f;
        float4 a0 = make_float4(0,0,0,0), a1 = make_float4(0,0,0,0);
        for (int i = beg; i < end; i += 8) {
            int idx = i + g;
            bool act = idx < end;
            int s = csrs[act ? idx : beg];
            const float* vp = Wh + (size_t)s * HID + l8 * 8;
            float4 v0 = *(const float4*)vp, v1 = *(const float4*)(vp + 4);
            float x = q0.x*v0.x + q0.y*v0.y + q0.z*v0.z + q0.w*v0.w
                    + q1.x*v1.x + q1.y*v1.y + q1.z*v1.z + q1.w*v1.w;
            x += __shfl_xor(x, 1); x += __shfl_xor(x, 2); x += __shfl_xor(x, 4);
            float e = x * sa;
            e = e > 0.f ? e : 0.2f * e;           // leaky_relu 0.2
            float wg = act ? __expf(e - ESHIFT) : 0.f;
            z += wg;
            a0.x += wg*v0.x; a0.y += wg*v0.y; a0.z += wg*v0.z; a0.w += wg*v0.w;
            a1.x += wg*v1.x; a1.y += wg*v1.y; a1.z += wg*v1.z; a1.w += wg*v1.w;
        }
        // merge 8 groups: pure-sum butterfly xor 8,16,32
        #pragma unroll
        for (int o = 8; o <= 32; o <<= 1) {
            z    += __shfl_xor(z, o);
            a0.x += __shfl_xor(a0.x, o); a0.y += __shfl_xor(a0.y, o);
            a0.z += __shfl_xor(a0.z, o); a0.w += __shfl_xor(a0.w, o);
            a1.x += __shfl_xor(a1.x, o); a1.y += __shfl_xor(a1.y, o);
            a1.z += __shfl_xor(a1.z, o); a1.w += __shfl_xor(a1.w, o);
        }
        if (g == 0) {
            float* ap = acc + (size_t)node * HID + l8 * 8;
            *(float4*)ap = a0; *(float4*)(ap + 4) = a1;
        }
        Zw += z;   // all lanes hold the full node z after butterfly; use lane 0's
    }
    __shared__ float shz[4];
    if (lane == 0) shz[w] = Zw;
    __syncthreads();
    if (t == 0) bsumz[blockIdx.x] = (shz[0] + shz[1]) + (shz[2] + shz[3]);
}

// in-block combine helper: invZ for one side from block sums
__device__ __forceinline__ float combine_invZ(const float* __restrict__ bsumz,
                                              int base, float* shred) {
    int t = threadIdx.x;
    float lz = 0.f;
    for (int i = t; i < NBE; i += 256) lz += bsumz[base + i];
    #pragma unroll
    for (int o = 32; o >= 1; o >>= 1) lz += __shfl_xor(lz, o);
    if ((t & 63) == 0) shred[t >> 6] = lz;
    __syncthreads();
    float Zt = (shred[0] + shred[1]) + (shred[2] + shred[3]);
    __syncthreads();
    return 1.f / Zt;
}

// ---- fused: combine + normalize + elu + LN(g0,b0) + GEMM(W1) -> Wh1, both sides ----
__global__ void normgemm2(const float* __restrict__ accS, const float* __restrict__ accT,
                          const float* __restrict__ bsumz,
                          const float* __restrict__ gS, const float* __restrict__ bS,
                          const float* __restrict__ gT, const float* __restrict__ bT,
                          const float* __restrict__ W1S, const float* __restrict__ W1T,
                          float* __restrict__ WhS, float* __restrict__ WhT, int n) {
    int side = blockIdx.x >= NBG;
    int blk = blockIdx.x - side * NBG;
    const float* acc = side ? accT : accS;
    const float* g = side ? gT : gS;
    const float* b = side ? bT : bS;
    const float* W1 = side ? W1T : W1S;
    float* Wh = side ? WhT : WhS;
    __shared__ float shred[4];
    float invZ = combine_invZ(bsumz, side * NBE, shred);
    __shared__ float Wl[64 * 64];
    int t = threadIdx.x;
    for (int i = t; i < 1024; i += 256)
        ((float4*)Wl)[i] = ((const float4*)W1)[i];
    __syncthreads();
    __shared__ float hrow[4][64];
    int w = t >> 6, lane = t & 63;
    float gl = g[lane], bl = b[lane];
    for (int node = blk * 4 + w; node < n; node += NBG * 4) {
        float v = acc[(size_t)node * HID + lane] * invZ;
        v = v > 0.f ? v : expm1f(v);         // elu
        float s = v, s2 = v * v;
        #pragma unroll
        for (int o = 32; o >= 1; o >>= 1) {
            s += __shfl_xor(s, o);
            s2 += __shfl_xor(s2, o);
        }
        float mean = s * (1.f / 64.f);
        float var = s2 * (1.f / 64.f) - mean * mean;
        float hn = gl * (v - mean) * rsqrtf(var + 1e-5f) + bl;
        hrow[w][lane] = hn;
        float o2 = 0.f;
        #pragma unroll
        for (int k = 0; k < 64; k++) o2 += hrow[w][k] * Wl[k * 64 + lane];
        Wh[(size_t)node * HID + lane] = o2;
    }
}

// ---- fused: combine(both sides) + normalize + elu + LN(g1,b1) + final MLP ----
__global__ void normfinal(const float* __restrict__ accS, const float* __restrict__ accT,
                          const float* __restrict__ bsumz,
                          const float* __restrict__ gS, const float* __restrict__ bS,
                          const float* __restrict__ gT, const float* __restrict__ bT,
                          const float* __restrict__ cW1, const float* __restrict__ cb1,
                          const float* __restrict__ cW2, const float* __restrict__ cb2,
                          float* __restrict__ out, int n) {
    __shared__ float shred[4];
    float invZS = combine_invZ(bsumz, 0, shred);
    float invZT = combine_invZ(bsumz, NBE, shred);
    __shared__ float W1l[64 * 32];
    __shared__ float W2l[32], B1l[32];
    int t = threadIdx.x;
    for (int i = t; i < 512; i += 256)
        ((float4*)W1l)[i] = ((const float4*)cW1)[i];
    if (t < 32) { W2l[t] = cW2[t]; B1l[t] = cb1[t]; }
    __syncthreads();
    float c2 = cb2[0];
    __shared__ float hrow[4][64];
    int w = t >> 6, lane = t & 63;
    int j = lane & 31;
    float glS = gS[lane], blS = bS[lane], glT = gT[lane], blT = bT[lane];
    for (int node = blockIdx.x * 4 + w; node < n; node += NBF * 4) {
        // side S
        float vS = accS[(size_t)node * HID + lane] * invZS;
        vS = vS > 0.f ? vS : expm1f(vS);
        float sA = vS, sB = vS * vS;
        #pragma unroll
        for (int o = 32; o >= 1; o >>= 1) { sA += __shfl_xor(sA, o); sB += __shfl_xor(sB, o); }
        float meanS = sA * (1.f / 64.f);
        float varS = sB * (1.f / 64.f) - meanS * meanS;
        float hS = glS * (vS - meanS) * rsqrtf(varS + 1e-5f) + blS;
        // side T
        float vT = accT[(size_t)node * HID + lane] * invZT;
        vT = vT > 0.f ? vT : expm1f(vT);
        sA = vT; sB = vT * vT;
        #pragma unroll
        for (int o = 32; o >= 1; o >>= 1) { sA += __shfl_xor(sA, o); sB += __shfl_xor(sB, o); }
        float meanT = sA * (1.f / 64.f);
        float varT = sB * (1.f / 64.f) - meanT * meanT;
        float hT = glT * (vT - meanT) * rsqrtf(varT + 1e-5f) + blT;
        hrow[w][lane] = hS + hT;
        // MLP (lanes 0-31 and 32-63 compute the same j redundantly)
        float a = B1l[j];
        #pragma unroll
        for (int k = 0; k < 64; k++) a += hrow[w][k] * W1l[k * 32 + j];
        a = fmaxf(a, 0.f);
        float p = a * W2l[j];
        #pragma unroll
        for (int o = 16; o >= 1; o >>= 1) p += __shfl_xor(p, o, 32);
        if (lane == 0) out[node] = 1.f / (1.f + expf(-(p + c2)));
    }
}

extern "C" void kernel_launch(void* const* d_in, const int* in_sizes, int n_in,
                              void* d_out, int out_size, void* d_ws, size_t ws_size,
                              hipStream_t stream) {
    const float* x   = (const float*)d_in[0];
    const int*   ei  = (const int*)d_in[1];
    const int*   tei = (const int*)d_in[3];
    const float* sW0 = (const float*)d_in[4],  *sa0 = (const float*)d_in[5];
    const float* sg0 = (const float*)d_in[6],  *sb0 = (const float*)d_in[7];
    const float* sW1 = (const float*)d_in[8],  *sa1 = (const float*)d_in[9];
    const float* sg1 = (const float*)d_in[10], *sb1 = (const float*)d_in[11];
    const float* tW0 = (const float*)d_in[12], *ta0 = (const float*)d_in[13];
    const float* tg0 = (const float*)d_in[14], *tb0 = (const float*)d_in[15];
    const float* tW1 = (const float*)d_in[16], *ta1 = (const float*)d_in[17];
    const float* tg1 = (const float*)d_in[18], *tb1 = (const float*)d_in[19];
    const float* cW1 = (const float*)d_in[20], *cb1 = (const float*)d_in[21];
    const float* cW2 = (const float*)d_in[22], *cb2 = (const float*)d_in[23];
    float* out = (float*)d_out;

    float* ws = (float*)d_ws;
    size_t o = 0;
    float* hS  = ws + o; o += (size_t)NN * HID;   // acc S (aliased across layers)
    float* hT  = ws + o; o += (size_t)NN * HID;   // acc T
    float* WhS = ws + o; o += (size_t)NN * HID;
    float* WhT = ws + o; o += (size_t)NN * HID;
    float* bsumz = ws + o; o += 2 * NBE;
    float* sum_a = ws + o; o += 4;
    int* ip = (int*)(ws + o);
    int* rowptrS = ip; ip += NN + 1;
    int* rowptrT = ip; ip += NN + 1;
    int* csrsS   = ip; ip += NE;
    int* csrsT   = ip; ip += NE;

    // CSR-build scratch aliases WhS/WhT (only live before the layers)
    int2* part   = (int2*)WhS;                 // 3.2M pairs = 25.6 MB
    int*  cnt    = (int*)WhT;                  // MATN+1
    int*  offm   = cnt + (MATN + 1);
    int*  rowtmp = offm + (MATN + 1);
    int*  bsum   = rowtmp + MATN;

    const int NSB = (MATN + 1023) / 1024;

    // ---- CSR build (both edge lists, bucket partition) ----
    bucket_hist<<<2 * NBLK, 256, 0, stream>>>(ei, tei, cnt);
    scanA<<<NSB, 256, 0, stream>>>(cnt, rowtmp, bsum, MATN);
    scanB<<<1, 256, 0, stream>>>(bsum, NSB);
    scanC<<<(MATN + 256) / 256, 256, 0, stream>>>(rowtmp, bsum, offm, MATN, 2 * NE);
    bucket_scatter<<<2 * NBLK, 256, 0, stream>>>(ei, tei, offm, part);
    bucket_csr<<<2 * NBUCK, 1024, 0, stream>>>(part, offm, rowptrS, rowptrT, csrsS, csrsT);

    prep4<<<1, 256, 0, stream>>>(sa0, sa1, ta0, ta1, sum_a);

    const int nbh = (NN + 63) / 64;

    // ---- layer 0 (batched S+T) ----
    gemm2_k8<<<2 * nbh, 256, 0, stream>>>(x, sW0, tW0, WhS, WhT, NN);
    edge_agg2<<<2 * NBE, 256, 0, stream>>>(WhS, WhT, rowptrS, rowptrT, csrsS, csrsT,
                                           sum_a, 0, 2, hS, hT, bsumz, NN);
    // L0 norm + L1 GEMM fused
    normgemm2<<<2 * NBG, 256, 0, stream>>>(hS, hT, bsumz,
                                           sg0, sb0, tg0, tb0, sW1, tW1, WhS, WhT, NN);
    // ---- layer 1 (batched S+T) ----
    edge_agg2<<<2 * NBE, 256, 0, stream>>>(WhS, WhT, rowptrS, rowptrT, csrsS, csrsT,
                                           sum_a, 1, 3, hS, hT, bsumz, NN);
    // L1 norm + final MLP fused
    normfinal<<<NBF, 256, 0, stream>>>(hS, hT, bsumz,
                                       sg1, sb1, tg1, tb1, cW1, cb1, cW2, cb2, out, NN);
}